// Round 5
// baseline (391.011 us; speedup 1.0000x reference)
//
#include <hip/hip_runtime.h>
#include <hip/hip_cooperative_groups.h>
#include <math.h>

namespace cg = cooperative_groups;

// Problem constants
#define Bn 2
#define Sn 512
#define Hn 128
#define NHn 4
#define Dn 32
#define BAGn 5
#define NMETAn 16
#define ROWS 1024
#define NBn 2
#define Tt 257

#define NEGF (-4294967295.0f)
#define INV_SQRT_D 0.17677669529663687f
#define SQRT_H 11.313708498984761f
#define EPS_EMB 1e-5f
#define EPSF 1e-8f

// workspace float offsets
#define OFF_QN    0
#define OFF_Q     131072
#define OFF_K     262144
#define OFF_V     393216
#define OFF_O     524288

static __device__ __forceinline__ float red64(float v) {
#pragma unroll
    for (int m = 1; m < 64; m <<= 1) v += __shfl_xor(v, m, 64);
    return v;
}
static __device__ __forceinline__ float red64max(float v) {
#pragma unroll
    for (int m = 1; m < 64; m <<= 1) v = fmaxf(v, __shfl_xor(v, m, 64));
    return v;
}

// LayerNorm over 128 channels held by threads 0..127 (2 waves). ALL 256
// threads call (contains barriers); waves 2/3 write unused wsum slots.
static __device__ __forceinline__ float ln128(float x, int t, float* wsum, float eps) {
    int w_ = t >> 6;
    float s1 = red64(x);
    if ((t & 63) == 0) wsum[w_] = s1;
    __syncthreads();
    float mean = (wsum[0] + wsum[1]) * (1.f / 128.f);
    float dlt = x - mean;
    float s2 = red64(dlt * dlt);
    if ((t & 63) == 0) wsum[4 + w_] = s2;
    __syncthreads();
    float rstd = rsqrtf((wsum[4] + wsum[5]) * (1.f / 128.f) + eps);
    return dlt * rstd;
}

// K=128 GEMV half: thread (h, kh) accumulates 64 of the 128 K-elements.
static __device__ __forceinline__ float gemv_half(const float* __restrict__ W,
                                                  const float* src, int h, int kh) {
    const float4* w4p = (const float4*)(W + h * 128 + kh * 64);
    const float* y0 = src + kh * 64;
    float a0 = 0.f, a1 = 0.f;
#pragma unroll 16
    for (int k4 = 0; k4 < 16; ++k4) {
        float4 w4 = w4p[k4];
        int k = k4 * 4;
        a0 += y0[k] * w4.x + y0[k + 1] * w4.y;
        a1 += y0[k + 2] * w4.z + y0[k + 3] * w4.w;
    }
    return a0 + a1;
}

// QKV projection for one row: qs -> Q, xsrc -> K,V ; adds bias + pos embs.
static __device__ __forceinline__ void qkv_row(
    int row, int t, const float* qs, const float* xsrc,
    float* parts, float* pk, float* pv,
    const float* __restrict__ QW, const float* __restrict__ Qb,
    const float* __restrict__ KW, const float* __restrict__ Kb,
    const float* __restrict__ VW, const float* __restrict__ Vb,
    const float* __restrict__ posK, const float* __restrict__ posV,
    float* __restrict__ Q, float* __restrict__ K, float* __restrict__ V, int nq)
{
    int h = t & 127, kh = t >> 7;
    const float4* qw4 = (const float4*)(QW + nq * 16384 + h * 128 + kh * 64);
    const float4* kw4 = (const float4*)(KW + nq * 16384 + h * 128 + kh * 64);
    const float4* vw4 = (const float4*)(VW + nq * 16384 + h * 128 + kh * 64);
    const float* q0p = qs + kh * 64;
    const float* x0p = xsrc + kh * 64;
    float aq0 = 0.f, ak0 = 0.f, av0 = 0.f;
#pragma unroll 8
    for (int k4 = 0; k4 < 16; ++k4) {
        float4 wq = qw4[k4], wk = kw4[k4], wv = vw4[k4];
        int k = k4 * 4;
        aq0 += q0p[k] * wq.x + q0p[k + 1] * wq.y + q0p[k + 2] * wq.z + q0p[k + 3] * wq.w;
        ak0 += x0p[k] * wk.x + x0p[k + 1] * wk.y + x0p[k + 2] * wk.z + x0p[k + 3] * wk.w;
        av0 += x0p[k] * wv.x + x0p[k + 1] * wv.y + x0p[k + 2] * wv.z + x0p[k + 3] * wv.w;
    }
    if (kh) { parts[h] = aq0; pk[h] = ak0; pv[h] = av0; }
    __syncthreads();
    if (!kh) {
        int s0 = row & (Sn - 1);
        Q[row * Hn + h] = aq0 + parts[h] + Qb[nq * Hn + h];
        K[row * Hn + h] = ak0 + pk[h] + Kb[nq * Hn + h] + posK[s0 * Hn + h];
        V[row * Hn + h] = av0 + pv[h] + Vb[nq * Hn + h] + posV[s0 * Hn + h];
    }
}

// ===========================================================================
// Embed phase: 1 row/block.
// sm: combs 0..256, xs 256..384, qs 384..512, parts 512..640, pk 640..768,
// pv 768..896, wsum 896..904.
// ===========================================================================
static __device__ __forceinline__ void embed_row(
    int row, int t, float* sm,
    const int* __restrict__ ids, const float* __restrict__ meta,
    const int* __restrict__ cats,
    const float* __restrict__ item_w, const float* __restrict__ cat_w,
    const float* __restrict__ numW, const float* __restrict__ numb,
    const float* __restrict__ fusW, const float* __restrict__ fusb,
    const float* __restrict__ elng, const float* __restrict__ elnb,
    const float* __restrict__ alng, const float* __restrict__ alnb,
    const float* __restrict__ QW, const float* __restrict__ Qb,
    const float* __restrict__ KW, const float* __restrict__ Kb,
    const float* __restrict__ VW, const float* __restrict__ Vb,
    const float* __restrict__ posK, const float* __restrict__ posV,
    float* __restrict__ Qn, float* __restrict__ Q,
    float* __restrict__ K, float* __restrict__ V)
{
    float* combs = sm;
    float* xs    = sm + 256;
    float* qs    = sm + 384;
    float* parts = sm + 512;
    float* pk    = sm + 640;
    float* pv    = sm + 768;
    float* wsum  = sm + 896;

    int id = ids[row];
    int ch = t & 127, kh = t >> 7, h = ch;

    if (t < 128) {
        combs[t] = item_w[id * Hn + t] * SQRT_H;
    } else if (t < 192) {
        int c = t - 128;
        float acc = numb[c];
#pragma unroll
        for (int m2 = 0; m2 < NMETAn; ++m2)
            acc += meta[row * NMETAn + m2] * numW[c * NMETAn + m2];
        combs[128 + c] = acc;
    } else {
        int c = t - 192;
        float ca = 0.f; int cnt = 0;
#pragma unroll
        for (int k2 = 0; k2 < BAGn; ++k2) {
            int cc2 = cats[row * BAGn + k2];
            if (cc2 != 0) { ca += cat_w[cc2 * 64 + c]; cnt++; }
        }
        combs[192 + c] = ca / (float)(cnt > 0 ? cnt : 1);
    }
    __syncthreads();

    // fusion GEMV: K=256, kh handles 128 each
    float A0;
    {
        const float4* w4p = (const float4*)(fusW + h * 256 + kh * 128);
        const float* c0 = combs + kh * 128;
        float a0 = 0.f, a1 = 0.f;
#pragma unroll 16
        for (int k4 = 0; k4 < 32; ++k4) {
            float4 w4 = w4p[k4];
            int k = k4 * 4;
            a0 += c0[k] * w4.x + c0[k + 1] * w4.y;
            a1 += c0[k + 2] * w4.z + c0[k + 3] * w4.w;
        }
        A0 = a0 + a1;
    }
    if (kh) parts[h] = A0;
    __syncthreads();
    float x = A0 + parts[h] + fusb[h];     // valid for kh==0; finite garbage else
    float dn = ln128(x, t, wsum, EPS_EMB);
    float xv = dn * elng[ch] + elnb[ch];
    xv = (id == 0) ? 0.f : xv;
    if (!kh) xs[h] = xv;
    __syncthreads();

    float x2 = xs[ch];
    float dn2 = ln128(x2, t, wsum, EPSF);
    float qn = dn2 * alng[ch] + alnb[ch];
    if (!kh) { qs[h] = qn; Qn[row * Hn + h] = qn; }
    __syncthreads();

    qkv_row(row, t, qs, xs, parts, pk, pv, QW, Qb, KW, Kb, VW, Vb,
            posK, posV, Q, K, V, 0);
}

// ===========================================================================
// FFN phase: 1 row/block.
// sm: ys 0..128, h1s 128..256, parts 256..384, pk 384..512, pv 512..640,
// wsum 640..648.
// ===========================================================================
static __device__ __forceinline__ void ffn_row(
    int row, int t, float* sm,
    const int* __restrict__ ids, float* __restrict__ Qn,
    const float* __restrict__ O,
    const float* __restrict__ flng, const float* __restrict__ flnb,
    const float* __restrict__ w1W, const float* __restrict__ w1b,
    const float* __restrict__ w2W, const float* __restrict__ w2b,
    const float* __restrict__ alng, const float* __restrict__ alnb,
    const float* __restrict__ QW, const float* __restrict__ Qb,
    const float* __restrict__ KW, const float* __restrict__ Kb,
    const float* __restrict__ VW, const float* __restrict__ Vb,
    const float* __restrict__ posK, const float* __restrict__ posV,
    float* __restrict__ Q, float* __restrict__ K, float* __restrict__ V,
    const float* __restrict__ llng, const float* __restrict__ llnb,
    float* __restrict__ out, int nb, int last)
{
    float* ys    = sm;
    float* h1s   = sm + 128;
    float* parts = sm + 256;
    float* pk    = sm + 384;
    float* pv    = sm + 512;
    float* wsum  = sm + 640;

    int ch = t & 127, kh = t >> 7, h = ch;

    float xin = Qn[row * Hn + ch] + O[row * Hn + ch];
    float dn = ln128(xin, t, wsum, EPSF);
    float yv = dn * flng[nb * Hn + ch] + flnb[nb * Hn + ch];
    if (!kh) ys[h] = yv;
    __syncthreads();

    float A0 = gemv_half(w1W + nb * 16384, ys, h, kh);
    if (kh) parts[h] = A0;
    __syncthreads();
    if (!kh) {
        float v0 = A0 + parts[h] + w1b[nb * Hn + h];
        h1s[h] = 0.5f * v0 * (1.f + erff(v0 * 0.70710678118654752f));
    }
    __syncthreads();

    float A1 = gemv_half(w2W + nb * 16384, h1s, h, kh);
    if (kh) parts[h] = A1;
    __syncthreads();
    if (!kh) {
        float z = A1 + parts[h] + w2b[nb * Hn + h] + ys[h];
        z = (ids[row] == 0) ? 0.f : z;
        h1s[h] = z;                     // overwrite gelu (all reads done)
    }
    __syncthreads();

    float zz = h1s[ch];
    float dn2 = ln128(zz, t, wsum, EPSF);

    if (last) {
        if (!kh) out[row * Hn + h] = dn2 * llng[h] + llnb[h];
        return;
    }

    int nq = nb + 1;
    float qn = dn2 * alng[nq * Hn + ch] + alnb[nq * Hn + ch];
    if (!kh) { ys[h] = qn; Qn[row * Hn + h] = qn; }
    __syncthreads();

    qkv_row(row, t, ys, h1s, parts, pk, pv, QW, Qb, KW, Kb, VW, Vb,
            posK, posV, Q, K, V, nq);
}

// ===========================================================================
// Attention v8: slim-LDS flash phase. K tile staged in LDS; V and tVw read
// straight from L2 in the PV loop (co-resident blocks share (b,h) -> hot);
// P and trow stay in REGISTERS and are broadcast with __shfl (per-lane src =
// bpermute) -- deletes Vt/Stile/trowT (10.4KB) and one barrier per tile.
// LDS: Kt 2112 + QTl 1040 + ql 132 + tlf 4 = 3288 floats = 13.2KB.
// ===========================================================================
static __device__ __forceinline__ void attn_phase(
    int b, int h, int i0, int t,
    const int* __restrict__ ids, const int* __restrict__ tmat,
    const float* __restrict__ Q, const float* __restrict__ K,
    const float* __restrict__ V,
    const float* __restrict__ tKw, const float* __restrict__ tVw,
    float* __restrict__ O,
    float* Kt, float* QTl, float* ql, int* tlf)
{
    __syncthreads();              // LDS handoff from previous phase
    if (t < 4) tlf[t] = (ids[b * Sn + i0 + t] == 0) ? 1 : 0;
    if (t < 128) {
        int q_ = t >> 5, d = t & 31;
        ql[q_ * 33 + d] = Q[(b * Sn + i0 + q_) * Hn + h * 32 + d];
    }
    __syncthreads();

    // fused QT: thread tt computes Q_i . timeK[tt] for the 4 queries
    for (int tt = t; tt < Tt; tt += 256) {
        const float4* tk4 = (const float4*)(tKw + tt * Hn + h * 32);
        float a0 = 0.f, a1 = 0.f, a2 = 0.f, a3 = 0.f;
#pragma unroll
        for (int dv = 0; dv < 8; ++dv) {
            float4 w4 = tk4[dv];
            int d = dv * 4;
            a0 += ql[d] * w4.x + ql[d + 1] * w4.y + ql[d + 2] * w4.z + ql[d + 3] * w4.w;
            a1 += ql[33 + d] * w4.x + ql[34 + d] * w4.y + ql[35 + d] * w4.z + ql[36 + d] * w4.w;
            a2 += ql[66 + d] * w4.x + ql[67 + d] * w4.y + ql[68 + d] * w4.z + ql[69 + d] * w4.w;
            a3 += ql[99 + d] * w4.x + ql[100 + d] * w4.y + ql[101 + d] * w4.z + ql[102 + d] * w4.w;
        }
        QTl[tt] = a0; QTl[260 + tt] = a1; QTl[520 + tt] = a2; QTl[780 + tt] = a3;
    }

    int tl_any = tlf[0] | tlf[1] | tlf[2] | tlf[3];
    int ntiles = tl_any ? 8 : ((i0 + 3) >> 6) + 1;

    int iq = t >> 6, jj = t & 63;
    int i_g = i0 + iq;
    int my_tl = tlf[iq];
    const int* trow = tmat + (b * Sn + i_g) * Sn;

    float qreg[32];
#pragma unroll
    for (int d = 0; d < 32; ++d) qreg[d] = ql[iq * 33 + d];

    int jq = jj >> 5, d = jj & 31;
    float m = -INFINITY, lsum = 0.f, acc = 0.f;

    for (int jt = 0; jt < ntiles; ++jt) {
        int j0 = jt * 64;
        __syncthreads();          // prior tile's Kt reads done (+QTl ready)
        for (int f = t; f < 64 * 8; f += 256) {
            int jl = f >> 3, dv = f & 7;
            float4 w4 = *(const float4*)(K + (b * Sn + j0 + jl) * Hn + h * 32 + dv * 4);
            float* kd = &Kt[jl * 33 + dv * 4];
            kd[0] = w4.x; kd[1] = w4.y; kd[2] = w4.z; kd[3] = w4.w;
        }
        __syncthreads();

        int active = my_tl || (j0 <= i_g);   // wave-uniform
        if (active) {
            int j = j0 + jj;
            float sv = NEGF;
            int tv = trow[j];
            if (!my_tl && j <= i_g) {
                float a = 0.f;
#pragma unroll
                for (int dd = 0; dd < 32; ++dd)
                    a += qreg[dd] * Kt[jj * 33 + dd];
                sv = (a + QTl[iq * 260 + tv]) * INV_SQRT_D;
            }
            float mt = red64max(sv);
            float mnew = fmaxf(m, mt);
            float alpha = expf(m - mnew);    // m=-inf first tile -> 0
            float p = expf(sv - mnew);
            lsum = lsum * alpha + red64(p);
            m = mnew;
            acc *= alpha;

            // PV: broadcast p/tv via shuffle, V + tVw from L2
            const float* Vb_ = V + (size_t)(b * Sn + j0) * Hn + h * 32 + d;
            const float* tVb_ = tVw + h * 32 + d;
            int base = jq * 32;
#pragma unroll 8
            for (int jl = base; jl < base + 32; ++jl) {
                float pp = __shfl(p, jl, 64);
                int tv2 = __shfl(tv, jl, 64);
                acc += pp * (Vb_[jl * Hn] + tVb_[tv2 * Hn]);
            }
        }
    }

    // finalize: sum the two jq halves, divide by l
    float a2 = acc + __shfl_xor(acc, 32, 64);
    if (jj < 32)
        O[(b * Sn + i_g) * Hn + h * 32 + d] = a2 / lsum;
}

// ===========================================================================
// Fused cooperative pipeline: 1024 blocks x 256 threads. LDS 13.2KB and
// VGPR<=128 (__launch_bounds__(256,4)) -> 4 blocks/CU even under the
// runtime's ~64KB-LDS occupancy model (round-3/4 evidence: 23.5KB gave
// maxb=2, rejecting grid 1024). embed/ffn: 1 row/block, 4-way staggered.
// attn: round-2 balanced mapping (co-resident slots {s,s+32,s+64,s+96},
// per-CU tile sum = 18) at 4-way overlap.
// ===========================================================================
__global__ __launch_bounds__(256, 4) void fused_kernel(
    const int* __restrict__ ids, const float* __restrict__ meta,
    const int* __restrict__ cats, const int* __restrict__ tmat,
    const float* __restrict__ item_w, const float* __restrict__ cat_w,
    const float* __restrict__ numW, const float* __restrict__ numb,
    const float* __restrict__ fusW, const float* __restrict__ fusb,
    const float* __restrict__ elng, const float* __restrict__ elnb,
    const float* __restrict__ posK, const float* __restrict__ posV,
    const float* __restrict__ tKw, const float* __restrict__ tVw,
    const float* __restrict__ alng, const float* __restrict__ alnb,
    const float* __restrict__ QW, const float* __restrict__ Qb,
    const float* __restrict__ KW, const float* __restrict__ Kb,
    const float* __restrict__ VW, const float* __restrict__ Vb,
    const float* __restrict__ flng, const float* __restrict__ flnb,
    const float* __restrict__ w1W, const float* __restrict__ w1b,
    const float* __restrict__ w2W, const float* __restrict__ w2b,
    const float* __restrict__ llng, const float* __restrict__ llnb,
    float* __restrict__ Qn, float* __restrict__ Q, float* __restrict__ K,
    float* __restrict__ V, float* __restrict__ O, float* __restrict__ out)
{
    cg::grid_group grid = cg::this_grid();
    __shared__ __align__(16) float sm[3288];
    int blk = blockIdx.x, t = threadIdx.x;

    // attn balance mapping (round-2 v7)
    int bh = blk & 7;
    int s  = blk >> 3;
    int g = s >> 5, r = s & 31;
    int mm;
    if      (g == 0) mm = r;
    else if (g == 1) mm = 127 - r;
    else if (g == 2) mm = 32 + r;
    else             mm = 95 - r;
    int ab = bh >> 2, ah = bh & 3, ai0 = mm * 4;

    embed_row(blk, t, sm, ids, meta, cats, item_w, cat_w, numW, numb,
              fusW, fusb, elng, elnb, alng, alnb, QW, Qb, KW, Kb, VW, Vb,
              posK, posV, Qn, Q, K, V);
    grid.sync();

    for (int nb = 0; nb < NBn; ++nb) {
        attn_phase(ab, ah, ai0, t, ids, tmat, Q, K, V, tKw, tVw, O,
                   sm, sm + 2112, sm + 3152, (int*)(sm + 3284));
        grid.sync();
        ffn_row(blk, t, sm, ids, Qn, O, flng, flnb, w1W, w1b, w2W, w2b,
                alng, alnb, QW, Qb, KW, Kb, VW, Vb, posK, posV,
                Q, K, V, llng, llnb, out, nb, (nb == NBn - 1) ? 1 : 0);
        if (nb == 0) grid.sync();
    }
}

// ===========================================================================
// Fallback kernels (same bodies, separate launches).
// ===========================================================================
__global__ __launch_bounds__(256, 4) void embed1_kernel(
    const int* ids, const float* meta, const int* cats,
    const float* item_w, const float* cat_w, const float* numW, const float* numb,
    const float* fusW, const float* fusb, const float* elng, const float* elnb,
    const float* alng, const float* alnb,
    const float* QW, const float* Qb, const float* KW, const float* Kb,
    const float* VW, const float* Vb, const float* posK, const float* posV,
    float* Qn, float* Q, float* K, float* V)
{
    __shared__ __align__(16) float sm[904];
    embed_row(blockIdx.x, threadIdx.x, sm, ids, meta, cats, item_w, cat_w,
              numW, numb, fusW, fusb, elng, elnb, alng, alnb, QW, Qb, KW, Kb,
              VW, Vb, posK, posV, Qn, Q, K, V);
}

__global__ __launch_bounds__(256, 4) void attn_kernel(
    const int* ids, const int* tmat,
    const float* Q, const float* K, const float* V,
    const float* tKw, const float* tVw, float* O)
{
    __shared__ __align__(16) float sm[3288];
    int blk = blockIdx.x, t = threadIdx.x;
    int bh = blk & 7;
    int s  = blk >> 3;
    int g = s >> 5, r = s & 31;
    int mm;
    if      (g == 0) mm = r;
    else if (g == 1) mm = 127 - r;
    else if (g == 2) mm = 32 + r;
    else             mm = 95 - r;
    int b = bh >> 2, h = bh & 3;
    attn_phase(b, h, mm * 4, t, ids, tmat, Q, K, V, tKw, tVw, O,
               sm, sm + 2112, sm + 3152, (int*)(sm + 3284));
}

__global__ __launch_bounds__(256, 4) void ffn1_kernel(
    const int* ids, float* Qn, const float* O,
    const float* flng, const float* flnb,
    const float* w1W, const float* w1b, const float* w2W, const float* w2b,
    const float* alng, const float* alnb,
    const float* QW, const float* Qb, const float* KW, const float* Kb,
    const float* VW, const float* Vb, const float* posK, const float* posV,
    float* Q, float* K, float* V,
    const float* llng, const float* llnb, float* out, int nb, int last)
{
    __shared__ __align__(16) float sm[648];
    ffn_row(blockIdx.x, threadIdx.x, sm, ids, Qn, O, flng, flnb, w1W, w1b,
            w2W, w2b, alng, alnb, QW, Qb, KW, Kb, VW, Vb, posK, posV,
            Q, K, V, llng, llnb, out, nb, last);
}

// ---------------------------------------------------------------------------
static int g_mode = -1;   // 1 = cooperative fused, 0 = multi-kernel fallback

extern "C" void kernel_launch(void* const* d_in, const int* in_sizes, int n_in,
                              void* d_out, int out_size, void* d_ws, size_t ws_size,
                              hipStream_t stream) {
    const int*   ids   = (const int*)  d_in[0];
    const float* meta  = (const float*)d_in[1];
    const int*   cats  = (const int*)  d_in[2];
    const int*   tmat  = (const int*)  d_in[3];
    const float* itemw = (const float*)d_in[4];
    const float* catw  = (const float*)d_in[5];
    const float* numW  = (const float*)d_in[6];
    const float* numb  = (const float*)d_in[7];
    const float* fusW  = (const float*)d_in[8];
    const float* fusb  = (const float*)d_in[9];
    const float* elng  = (const float*)d_in[10];
    const float* elnb  = (const float*)d_in[11];
    const float* posK  = (const float*)d_in[12];
    const float* posV  = (const float*)d_in[13];
    const float* tKw   = (const float*)d_in[14];
    const float* tVw   = (const float*)d_in[15];
    const float* alng  = (const float*)d_in[16];
    const float* alnb  = (const float*)d_in[17];
    const float* QW    = (const float*)d_in[18];
    const float* Qb    = (const float*)d_in[19];
    const float* KW    = (const float*)d_in[20];
    const float* Kb    = (const float*)d_in[21];
    const float* VW    = (const float*)d_in[22];
    const float* Vb    = (const float*)d_in[23];
    const float* flng  = (const float*)d_in[24];
    const float* flnb  = (const float*)d_in[25];
    const float* w1W   = (const float*)d_in[26];
    const float* w1b   = (const float*)d_in[27];
    const float* w2W   = (const float*)d_in[28];
    const float* w2b   = (const float*)d_in[29];
    const float* llng  = (const float*)d_in[30];
    const float* llnb  = (const float*)d_in[31];
    (void)in_sizes; (void)n_in; (void)out_size; (void)ws_size;

    float* ws = (float*)d_ws;
    float* Qnp = ws + OFF_QN;
    float* Qp  = ws + OFF_Q;
    float* Kp  = ws + OFF_K;
    float* Vp  = ws + OFF_V;
    float* Op  = ws + OFF_O;
    float* outp = (float*)d_out;

    if (g_mode < 0) {
        // Host-side queries only (no stream ops) — graph-capture safe.
        int dev = 0;
        (void)hipGetDevice(&dev);
        int coop = 0;
        (void)hipDeviceGetAttribute(&coop, hipDeviceAttributeCooperativeLaunch, dev);
        int ncu = 0;
        (void)hipDeviceGetAttribute(&ncu, hipDeviceAttributeMultiprocessorCount, dev);
        int maxb = 0;
        hipError_t oe = hipOccupancyMaxActiveBlocksPerMultiprocessor(
            &maxb, fused_kernel, 256, 0);
        g_mode = (coop && oe == hipSuccess && (long)maxb * (long)ncu >= 1024) ? 1 : 0;
    }

    if (g_mode == 1) {
        void* args[] = {
            (void*)&ids, (void*)&meta, (void*)&cats, (void*)&tmat,
            (void*)&itemw, (void*)&catw, (void*)&numW, (void*)&numb,
            (void*)&fusW, (void*)&fusb, (void*)&elng, (void*)&elnb,
            (void*)&posK, (void*)&posV, (void*)&tKw, (void*)&tVw,
            (void*)&alng, (void*)&alnb, (void*)&QW, (void*)&Qb,
            (void*)&KW, (void*)&Kb, (void*)&VW, (void*)&Vb,
            (void*)&flng, (void*)&flnb, (void*)&w1W, (void*)&w1b,
            (void*)&w2W, (void*)&w2b, (void*)&llng, (void*)&llnb,
            (void*)&Qnp, (void*)&Qp, (void*)&Kp, (void*)&Vp, (void*)&Op,
            (void*)&outp
        };
        hipError_t e = hipLaunchCooperativeKernel((void*)fused_kernel,
                                                  dim3(1024), dim3(256),
                                                  args, 0, stream);
        if (e == hipSuccess) return;
        g_mode = 0;   // validation failed -> nothing enqueued -> fall through
    }

    // ---- fallback: five-kernel pipeline with the same bodies ----
    embed1_kernel<<<ROWS, 256, 0, stream>>>(
        ids, meta, cats, itemw, catw, numW, numb, fusW, fusb, elng, elnb,
        alng, alnb, QW, Qb, KW, Kb, VW, Vb, posK, posV, Qnp, Qp, Kp, Vp);
    for (int nb = 0; nb < NBn; ++nb) {
        attn_kernel<<<1024, 256, 0, stream>>>(ids, tmat, Qp, Kp, Vp, tKw, tVw, Op);
        ffn1_kernel<<<ROWS, 256, 0, stream>>>(
            ids, Qnp, Op, flng, flnb, w1W, w1b, w2W, w2b,
            alng, alnb, QW, Qb, KW, Kb, VW, Vb, posK, posV,
            Qp, Kp, Vp, llng, llnb, outp, nb, (nb == NBn - 1) ? 1 : 0);
    }
}

// Round 6
// 286.808 us; speedup vs baseline: 1.3633x; 1.3633x over previous
//
#include <hip/hip_runtime.h>
#include <math.h>

// Problem constants
#define Bn 2
#define Sn 512
#define Hn 128
#define NHn 4
#define Dn 32
#define BAGn 5
#define NMETAn 16
#define ROWS 1024
#define NBn 2
#define Tt 257

#define NEGF (-4294967295.0f)
#define INV_SQRT_D 0.17677669529663687f
#define SQRT_H 11.313708498984761f
#define EPS_EMB 1e-5f
#define EPSF 1e-8f

// workspace float offsets
#define OFF_QN    0
#define OFF_Q     131072
#define OFF_K     262144
#define OFF_V     393216
#define OFF_O     524288

static __device__ __forceinline__ float red64(float v) {
#pragma unroll
    for (int m = 1; m < 64; m <<= 1) v += __shfl_xor(v, m, 64);
    return v;
}
static __device__ __forceinline__ float red64max(float v) {
#pragma unroll
    for (int m = 1; m < 64; m <<= 1) v = fmaxf(v, __shfl_xor(v, m, 64));
    return v;
}

// LayerNorm over 128 channels held by threads 0..127 (2 waves). ALL 256
// threads call (contains barriers); waves 2/3 write unused wsum slots.
static __device__ __forceinline__ float ln128(float x, int t, float* wsum, float eps) {
    int w_ = t >> 6;
    float s1 = red64(x);
    if ((t & 63) == 0) wsum[w_] = s1;
    __syncthreads();
    float mean = (wsum[0] + wsum[1]) * (1.f / 128.f);
    float dlt = x - mean;
    float s2 = red64(dlt * dlt);
    if ((t & 63) == 0) wsum[4 + w_] = s2;
    __syncthreads();
    float rstd = rsqrtf((wsum[4] + wsum[5]) * (1.f / 128.f) + eps);
    return dlt * rstd;
}

// K=128 GEMV half: thread (h, kh) accumulates 64 of the 128 K-elements.
static __device__ __forceinline__ float gemv_half(const float* __restrict__ W,
                                                  const float* src, int h, int kh) {
    const float4* w4p = (const float4*)(W + h * 128 + kh * 64);
    const float* y0 = src + kh * 64;
    float a0 = 0.f, a1 = 0.f;
#pragma unroll 16
    for (int k4 = 0; k4 < 16; ++k4) {
        float4 w4 = w4p[k4];
        int k = k4 * 4;
        a0 += y0[k] * w4.x + y0[k + 1] * w4.y;
        a1 += y0[k + 2] * w4.z + y0[k + 3] * w4.w;
    }
    return a0 + a1;
}

// QKV projection for one row: qs -> Q, xsrc -> K,V ; adds bias + pos embs.
static __device__ __forceinline__ void qkv_row(
    int row, int t, const float* qs, const float* xsrc,
    float* parts, float* pk, float* pv,
    const float* __restrict__ QW, const float* __restrict__ Qb,
    const float* __restrict__ KW, const float* __restrict__ Kb,
    const float* __restrict__ VW, const float* __restrict__ Vb,
    const float* __restrict__ posK, const float* __restrict__ posV,
    float* __restrict__ Q, float* __restrict__ K, float* __restrict__ V, int nq)
{
    int h = t & 127, kh = t >> 7;
    const float4* qw4 = (const float4*)(QW + nq * 16384 + h * 128 + kh * 64);
    const float4* kw4 = (const float4*)(KW + nq * 16384 + h * 128 + kh * 64);
    const float4* vw4 = (const float4*)(VW + nq * 16384 + h * 128 + kh * 64);
    const float* q0p = qs + kh * 64;
    const float* x0p = xsrc + kh * 64;
    float aq0 = 0.f, ak0 = 0.f, av0 = 0.f;
#pragma unroll 8
    for (int k4 = 0; k4 < 16; ++k4) {
        float4 wq = qw4[k4], wk = kw4[k4], wv = vw4[k4];
        int k = k4 * 4;
        aq0 += q0p[k] * wq.x + q0p[k + 1] * wq.y + q0p[k + 2] * wq.z + q0p[k + 3] * wq.w;
        ak0 += x0p[k] * wk.x + x0p[k + 1] * wk.y + x0p[k + 2] * wk.z + x0p[k + 3] * wk.w;
        av0 += x0p[k] * wv.x + x0p[k + 1] * wv.y + x0p[k + 2] * wv.z + x0p[k + 3] * wv.w;
    }
    if (kh) { parts[h] = aq0; pk[h] = ak0; pv[h] = av0; }
    __syncthreads();
    if (!kh) {
        int s0 = row & (Sn - 1);
        Q[row * Hn + h] = aq0 + parts[h] + Qb[nq * Hn + h];
        K[row * Hn + h] = ak0 + pk[h] + Kb[nq * Hn + h] + posK[s0 * Hn + h];
        V[row * Hn + h] = av0 + pv[h] + Vb[nq * Hn + h] + posV[s0 * Hn + h];
    }
}

// ===========================================================================
// Embed: 1 row/block, 1024 blocks (4 blocks/CU co-resident, tiny LDS).
// Body correctness-proven in round 5. NO __launch_bounds__ occupancy forcing
// (round-5 post-mortem: VGPR cap 64 destroyed load ILP).
// ===========================================================================
static __device__ __forceinline__ void embed_row(
    int row, int t, float* sm,
    const int* __restrict__ ids, const float* __restrict__ meta,
    const int* __restrict__ cats,
    const float* __restrict__ item_w, const float* __restrict__ cat_w,
    const float* __restrict__ numW, const float* __restrict__ numb,
    const float* __restrict__ fusW, const float* __restrict__ fusb,
    const float* __restrict__ elng, const float* __restrict__ elnb,
    const float* __restrict__ alng, const float* __restrict__ alnb,
    const float* __restrict__ QW, const float* __restrict__ Qb,
    const float* __restrict__ KW, const float* __restrict__ Kb,
    const float* __restrict__ VW, const float* __restrict__ Vb,
    const float* __restrict__ posK, const float* __restrict__ posV,
    float* __restrict__ Qn, float* __restrict__ Q,
    float* __restrict__ K, float* __restrict__ V)
{
    float* combs = sm;          // 256
    float* xs    = sm + 256;    // 128
    float* qs    = sm + 384;    // 128
    float* parts = sm + 512;    // 128
    float* pk    = sm + 640;    // 128
    float* pv    = sm + 768;    // 128
    float* wsum  = sm + 896;    // 8

    int id = ids[row];
    int ch = t & 127, kh = t >> 7, h = ch;

    if (t < 128) {
        combs[t] = item_w[id * Hn + t] * SQRT_H;
    } else if (t < 192) {
        int c = t - 128;
        float acc = numb[c];
#pragma unroll
        for (int m2 = 0; m2 < NMETAn; ++m2)
            acc += meta[row * NMETAn + m2] * numW[c * NMETAn + m2];
        combs[128 + c] = acc;
    } else {
        int c = t - 192;
        float ca = 0.f; int cnt = 0;
#pragma unroll
        for (int k2 = 0; k2 < BAGn; ++k2) {
            int cc2 = cats[row * BAGn + k2];
            if (cc2 != 0) { ca += cat_w[cc2 * 64 + c]; cnt++; }
        }
        combs[192 + c] = ca / (float)(cnt > 0 ? cnt : 1);
    }
    __syncthreads();

    // fusion GEMV: K=256, kh handles 128 each
    float A0;
    {
        const float4* w4p = (const float4*)(fusW + h * 256 + kh * 128);
        const float* c0 = combs + kh * 128;
        float a0 = 0.f, a1 = 0.f;
#pragma unroll 16
        for (int k4 = 0; k4 < 32; ++k4) {
            float4 w4 = w4p[k4];
            int k = k4 * 4;
            a0 += c0[k] * w4.x + c0[k + 1] * w4.y;
            a1 += c0[k + 2] * w4.z + c0[k + 3] * w4.w;
        }
        A0 = a0 + a1;
    }
    if (kh) parts[h] = A0;
    __syncthreads();
    float x = A0 + parts[h] + fusb[h];     // valid for kh==0; finite garbage else
    float dn = ln128(x, t, wsum, EPS_EMB);
    float xv = dn * elng[ch] + elnb[ch];
    xv = (id == 0) ? 0.f : xv;
    if (!kh) xs[h] = xv;
    __syncthreads();

    float x2 = xs[ch];
    float dn2 = ln128(x2, t, wsum, EPSF);
    float qn = dn2 * alng[ch] + alnb[ch];
    if (!kh) { qs[h] = qn; Qn[row * Hn + h] = qn; }
    __syncthreads();

    qkv_row(row, t, qs, xs, parts, pk, pv, QW, Qb, KW, Kb, VW, Vb,
            posK, posV, Q, K, V, 0);
}

// ===========================================================================
// FFN: 1 row/block, 1024 blocks. Body correctness-proven in round 5.
// ===========================================================================
static __device__ __forceinline__ void ffn_row(
    int row, int t, float* sm,
    const int* __restrict__ ids, float* __restrict__ Qn,
    const float* __restrict__ O,
    const float* __restrict__ flng, const float* __restrict__ flnb,
    const float* __restrict__ w1W, const float* __restrict__ w1b,
    const float* __restrict__ w2W, const float* __restrict__ w2b,
    const float* __restrict__ alng, const float* __restrict__ alnb,
    const float* __restrict__ QW, const float* __restrict__ Qb,
    const float* __restrict__ KW, const float* __restrict__ Kb,
    const float* __restrict__ VW, const float* __restrict__ Vb,
    const float* __restrict__ posK, const float* __restrict__ posV,
    float* __restrict__ Q, float* __restrict__ K, float* __restrict__ V,
    const float* __restrict__ llng, const float* __restrict__ llnb,
    float* __restrict__ out, int nb, int last)
{
    float* ys    = sm;          // 128
    float* h1s   = sm + 128;    // 128
    float* parts = sm + 256;    // 128
    float* pk    = sm + 384;    // 128
    float* pv    = sm + 512;    // 128
    float* wsum  = sm + 640;    // 8

    int ch = t & 127, kh = t >> 7, h = ch;

    float xin = Qn[row * Hn + ch] + O[row * Hn + ch];
    float dn = ln128(xin, t, wsum, EPSF);
    float yv = dn * flng[nb * Hn + ch] + flnb[nb * Hn + ch];
    if (!kh) ys[h] = yv;
    __syncthreads();

    float A0 = gemv_half(w1W + nb * 16384, ys, h, kh);
    if (kh) parts[h] = A0;
    __syncthreads();
    if (!kh) {
        float v0 = A0 + parts[h] + w1b[nb * Hn + h];
        h1s[h] = 0.5f * v0 * (1.f + erff(v0 * 0.70710678118654752f));
    }
    __syncthreads();

    float A1 = gemv_half(w2W + nb * 16384, h1s, h, kh);
    if (kh) parts[h] = A1;
    __syncthreads();
    if (!kh) {
        float z = A1 + parts[h] + w2b[nb * Hn + h] + ys[h];
        z = (ids[row] == 0) ? 0.f : z;
        h1s[h] = z;                     // overwrite gelu (all reads done)
    }
    __syncthreads();

    float zz = h1s[ch];
    float dn2 = ln128(zz, t, wsum, EPSF);

    if (last) {
        if (!kh) out[row * Hn + h] = dn2 * llng[h] + llnb[h];
        return;
    }

    int nq = nb + 1;
    float qn = dn2 * alng[nq * Hn + ch] + alnb[nq * Hn + ch];
    if (!kh) { ys[h] = qn; Qn[row * Hn + h] = qn; }
    __syncthreads();

    qkv_row(row, t, ys, h1s, parts, pk, pv, QW, Qb, KW, Kb, VW, Vb,
            posK, posV, Q, K, V, nq);
}

// ===========================================================================
// Attention (round-2 v7 VERBATIM — measured 34us): flash-style online
// softmax, K+V staged in LDS, Stile/trowT in LDS, 4-query phase per block.
// ===========================================================================
static __device__ __forceinline__ void attn_phase(
    int b, int h, int i0, int t,
    const int* __restrict__ ids, const int* __restrict__ tmat,
    const float* __restrict__ Q, const float* __restrict__ K,
    const float* __restrict__ V,
    const float* __restrict__ tKw, const float* __restrict__ tVw,
    float* __restrict__ O,
    float* Kt, float* Vt, float* Stile, int* trowT,
    float* QTl, float* ql, int* tlf)
{
    if (t < 4) tlf[t] = (ids[b * Sn + i0 + t] == 0) ? 1 : 0;
    if (t < 128) {
        int q_ = t >> 5, d = t & 31;
        ql[q_ * 33 + d] = Q[(b * Sn + i0 + q_) * Hn + h * 32 + d];
    }
    __syncthreads();

    // fused QT: thread tt computes Q_i . timeK[tt] for the 4 queries
    for (int tt = t; tt < Tt; tt += 256) {
        const float4* tk4 = (const float4*)(tKw + tt * Hn + h * 32);
        float a0 = 0.f, a1 = 0.f, a2 = 0.f, a3 = 0.f;
#pragma unroll
        for (int dv = 0; dv < 8; ++dv) {
            float4 w4 = tk4[dv];
            int d = dv * 4;
            a0 += ql[d] * w4.x + ql[d + 1] * w4.y + ql[d + 2] * w4.z + ql[d + 3] * w4.w;
            a1 += ql[33 + d] * w4.x + ql[34 + d] * w4.y + ql[35 + d] * w4.z + ql[36 + d] * w4.w;
            a2 += ql[66 + d] * w4.x + ql[67 + d] * w4.y + ql[68 + d] * w4.z + ql[69 + d] * w4.w;
            a3 += ql[99 + d] * w4.x + ql[100 + d] * w4.y + ql[101 + d] * w4.z + ql[102 + d] * w4.w;
        }
        QTl[tt] = a0; QTl[260 + tt] = a1; QTl[520 + tt] = a2; QTl[780 + tt] = a3;
    }

    int tl_any = tlf[0] | tlf[1] | tlf[2] | tlf[3];
    int ntiles = tl_any ? 8 : ((i0 + 3) >> 6) + 1;

    int iq = t >> 6, jj = t & 63;
    int i_g = i0 + iq;
    int my_tl = tlf[iq];
    const int* trow = tmat + (b * Sn + i_g) * Sn;

    float qreg[32];
#pragma unroll
    for (int d = 0; d < 32; ++d) qreg[d] = ql[iq * 33 + d];

    int jq = jj >> 5, d = jj & 31;
    float m = -INFINITY, lsum = 0.f, acc = 0.f;

    for (int jt = 0; jt < ntiles; ++jt) {
        int j0 = jt * 64;
        __syncthreads();           // prior PV done before re-staging
        for (int f = t; f < 64 * 8; f += 256) {
            int jl = f >> 3, dv = f & 7;
            const float* src = K + (b * Sn + j0 + jl) * Hn + h * 32 + dv * 4;
            float4 w4 = *(const float4*)src;
            float* kd = &Kt[jl * 33 + dv * 4];
            kd[0] = w4.x; kd[1] = w4.y; kd[2] = w4.z; kd[3] = w4.w;
            float4 v4 = *(const float4*)(V + (b * Sn + j0 + jl) * Hn + h * 32 + dv * 4);
            float* vd = &Vt[jl * 33 + dv * 4];
            vd[0] = v4.x; vd[1] = v4.y; vd[2] = v4.z; vd[3] = v4.w;
        }
        __syncthreads();

        int active = my_tl || (j0 <= i_g);   // wave-uniform
        if (active) {
            int j = j0 + jj;
            float sv = NEGF;
            int tv = trow[j];
            if (!my_tl && j <= i_g) {
                float a = 0.f;
#pragma unroll
                for (int dd = 0; dd < 32; ++dd)
                    a += qreg[dd] * Kt[jj * 33 + dd];
                sv = (a + QTl[iq * 260 + tv]) * INV_SQRT_D;
            }
            float mt = red64max(sv);
            float mnew = fmaxf(m, mt);
            float alpha = expf(m - mnew);    // m=-inf first tile -> 0
            float p = expf(sv - mnew);
            lsum = lsum * alpha + red64(p);
            m = mnew;
            acc *= alpha;
            Stile[iq * 64 + jj] = p;
            trowT[iq * 64 + jj] = tv;
        }
        __syncthreads();           // Stile/Vt visible (also keeps waves aligned)
        if (active) {
            int base = jq * 32;
#pragma unroll 8
            for (int jl = base; jl < base + 32; ++jl) {
                float pp = Stile[iq * 64 + jl];
                int tv2 = trowT[iq * 64 + jl];
                acc += pp * (Vt[jl * 33 + d] + tVw[tv2 * Hn + h * 32 + d]);
            }
        }
    }

    // finalize: sum the two jq halves, divide by l
    float a2 = acc + __shfl_xor(acc, 32, 64);
    if (jj < 32)
        O[(b * Sn + i_g) * Hn + h * 32 + d] = a2 / lsum;
}

__global__ __launch_bounds__(256) void attn_kernel(
    const int* ids, const int* tmat,
    const float* Q, const float* K, const float* V,
    const float* tKw, const float* tVw, float* O)
{
    __shared__ float Kt[64 * 33];
    __shared__ float Vt[64 * 33];
    __shared__ float Stile[4 * 64];
    __shared__ int   trowT[4 * 64];
    __shared__ float QTl[4 * 260];
    __shared__ float ql[4 * 33];
    __shared__ int tlf[4];
    int blk = blockIdx.x, t = threadIdx.x;
    int bh = blk & 7;               // consecutive blocks span all (b,h)
    int s  = blk >> 3;              // phase slot 0..127
    int g = s >> 5, r = s & 31;
    int mm;
    if      (g == 0) mm = r;        // tiles 1-2
    else if (g == 1) mm = 127 - r;  // tiles 7-8
    else if (g == 2) mm = 32 + r;   // tiles 3-4
    else             mm = 95 - r;   // tiles 5-6  -> per-CU sum always 18
    int b = bh >> 2, h = bh & 3;
    attn_phase(b, h, mm * 4, t, ids, tmat, Q, K, V, tKw, tVw, O,
               Kt, Vt, Stile, trowT, QTl, ql, tlf);
}

__global__ __launch_bounds__(256) void embed1_kernel(
    const int* ids, const float* meta, const int* cats,
    const float* item_w, const float* cat_w, const float* numW, const float* numb,
    const float* fusW, const float* fusb, const float* elng, const float* elnb,
    const float* alng, const float* alnb,
    const float* QW, const float* Qb, const float* KW, const float* Kb,
    const float* VW, const float* Vb, const float* posK, const float* posV,
    float* Qn, float* Q, float* K, float* V)
{
    __shared__ __align__(16) float sm[904];
    embed_row(blockIdx.x, threadIdx.x, sm, ids, meta, cats, item_w, cat_w,
              numW, numb, fusW, fusb, elng, elnb, alng, alnb, QW, Qb, KW, Kb,
              VW, Vb, posK, posV, Qn, Q, K, V);
}

__global__ __launch_bounds__(256) void ffn1_kernel(
    const int* ids, float* Qn, const float* O,
    const float* flng, const float* flnb,
    const float* w1W, const float* w1b, const float* w2W, const float* w2b,
    const float* alng, const float* alnb,
    const float* QW, const float* Qb, const float* KW, const float* Kb,
    const float* VW, const float* Vb, const float* posK, const float* posV,
    float* Q, float* K, float* V,
    const float* llng, const float* llnb, float* out, int nb, int last)
{
    __shared__ __align__(16) float sm[648];
    ffn_row(blockIdx.x, threadIdx.x, sm, ids, Qn, O, flng, flnb, w1W, w1b,
            w2W, w2b, alng, alnb, QW, Qb, KW, Kb, VW, Vb, posK, posV,
            Q, K, V, llng, llnb, out, nb, last);
}

// ---------------------------------------------------------------------------
extern "C" void kernel_launch(void* const* d_in, const int* in_sizes, int n_in,
                              void* d_out, int out_size, void* d_ws, size_t ws_size,
                              hipStream_t stream) {
    const int*   ids   = (const int*)  d_in[0];
    const float* meta  = (const float*)d_in[1];
    const int*   cats  = (const int*)  d_in[2];
    const int*   tmat  = (const int*)  d_in[3];
    const float* itemw = (const float*)d_in[4];
    const float* catw  = (const float*)d_in[5];
    const float* numW  = (const float*)d_in[6];
    const float* numb  = (const float*)d_in[7];
    const float* fusW  = (const float*)d_in[8];
    const float* fusb  = (const float*)d_in[9];
    const float* elng  = (const float*)d_in[10];
    const float* elnb  = (const float*)d_in[11];
    const float* posK  = (const float*)d_in[12];
    const float* posV  = (const float*)d_in[13];
    const float* tKw   = (const float*)d_in[14];
    const float* tVw   = (const float*)d_in[15];
    const float* alng  = (const float*)d_in[16];
    const float* alnb  = (const float*)d_in[17];
    const float* QW    = (const float*)d_in[18];
    const float* Qb    = (const float*)d_in[19];
    const float* KW    = (const float*)d_in[20];
    const float* Kb    = (const float*)d_in[21];
    const float* VW    = (const float*)d_in[22];
    const float* Vb    = (const float*)d_in[23];
    const float* flng  = (const float*)d_in[24];
    const float* flnb  = (const float*)d_in[25];
    const float* w1W   = (const float*)d_in[26];
    const float* w1b   = (const float*)d_in[27];
    const float* w2W   = (const float*)d_in[28];
    const float* w2b   = (const float*)d_in[29];
    const float* llng  = (const float*)d_in[30];
    const float* llnb  = (const float*)d_in[31];
    (void)in_sizes; (void)n_in; (void)out_size; (void)ws_size;

    float* ws = (float*)d_ws;
    float* Qnp = ws + OFF_QN;
    float* Qp  = ws + OFF_Q;
    float* Kp  = ws + OFF_K;
    float* Vp  = ws + OFF_V;
    float* Op  = ws + OFF_O;
    float* outp = (float*)d_out;

    embed1_kernel<<<ROWS, 256, 0, stream>>>(
        ids, meta, cats, itemw, catw, numW, numb, fusW, fusb, elng, elnb,
        alng, alnb, QW, Qb, KW, Kb, VW, Vb, posK, posV, Qnp, Qp, Kp, Vp);
    for (int nb = 0; nb < NBn; ++nb) {
        attn_kernel<<<1024, 256, 0, stream>>>(ids, tmat, Qp, Kp, Vp, tKw, tVw, Op);
        ffn1_kernel<<<ROWS, 256, 0, stream>>>(
            ids, Qnp, Op, flng, flnb, w1W, w1b, w2W, w2b,
            alng, alnb, QW, Qb, KW, Kb, VW, Vb, posK, posV,
            Qp, Kp, Vp, llng, llnb, outp, nb, (nb == NBn - 1) ? 1 : 0);
    }
}

// Round 7
// 228.971 us; speedup vs baseline: 1.7077x; 1.2526x over previous
//
#include <hip/hip_runtime.h>
#include <math.h>

// Problem constants
#define Bn 2
#define Sn 512
#define Hn 128
#define NHn 4
#define Dn 32
#define BAGn 5
#define NMETAn 16
#define ROWS 1024
#define NBn 2
#define Tt 257

#define NEGF (-4294967295.0f)
#define INV_SQRT_D 0.17677669529663687f
#define SQRT_H 11.313708498984761f
#define EPS_EMB 1e-5f
#define EPSF 1e-8f

// workspace float offsets
#define OFF_QN    0
#define OFF_Q     131072
#define OFF_K     262144
#define OFF_V     393216
#define OFF_O     524288

static __device__ __forceinline__ float red64(float v) {
#pragma unroll
    for (int m = 1; m < 64; m <<= 1) v += __shfl_xor(v, m, 64);
    return v;
}
static __device__ __forceinline__ float red64max(float v) {
#pragma unroll
    for (int m = 1; m < 64; m <<= 1) v = fmaxf(v, __shfl_xor(v, m, 64));
    return v;
}
static __device__ __forceinline__ float dot4(float4 a, float4 b) {
    return a.x * b.x + a.y * b.y + a.z * b.z + a.w * b.w;
}
// combine partial dot across the 4-lane k-split group (all 4 lanes get sum)
static __device__ __forceinline__ float red4(float v) {
    v += __shfl_xor(v, 1, 64);
    v += __shfl_xor(v, 2, 64);
    return v;
}

// ===========================================================================
// Embed + embLN + keep + attnLN(0) + QKV(0). 2 rows/block, 512 blocks.
// ROUND-6 POST-MORTEM: GEMVs with thread->weight-row mapping make each wave
// touch 64 distinct cache lines per load instruction (rows 512B apart) ->
// TA/L1-throughput-bound (~2048-3072 TA-cyc/wave/stage), VALUBusy ~10%.
// FIX: 4-lane k-split -- lane q=t&3 of group g=t>>2 reads float4 at
// k=4q+16j of row h=p*64+g: 16 rows x 1 fully-used 64B line per instruction
// (4x fewer line-touches), combine via 2 shfl_xor. Same bytes, same FMAs.
// ===========================================================================
__global__ __launch_bounds__(256) void embed_qkv_kernel(
    const int* __restrict__ ids, const float* __restrict__ meta,
    const int* __restrict__ cats,
    const float* __restrict__ item_w, const float* __restrict__ cat_w,
    const float* __restrict__ numW, const float* __restrict__ numb,
    const float* __restrict__ fusW, const float* __restrict__ fusb,
    const float* __restrict__ elng, const float* __restrict__ elnb,
    const float* __restrict__ alng, const float* __restrict__ alnb,
    const float* __restrict__ QW, const float* __restrict__ Qb,
    const float* __restrict__ KW, const float* __restrict__ Kb,
    const float* __restrict__ VW, const float* __restrict__ Vb,
    const float* __restrict__ posK, const float* __restrict__ posV,
    float* __restrict__ Qn, float* __restrict__ Q,
    float* __restrict__ K, float* __restrict__ V)
{
    int r0 = blockIdx.x * 2, t = threadIdx.x;
    __shared__ __align__(16) float combs[512];
    __shared__ __align__(16) float xs[256];
    __shared__ __align__(16) float qs[256];
    __shared__ float wsum[8];
    __shared__ int idl[2];
    if (t < 2) idl[t] = ids[r0 + t];
    __syncthreads();
    { int r = t >> 7, c = t & 127; combs[r * 256 + c] = item_w[idl[r] * Hn + c] * SQRT_H; }
    if (t < 128) {
        int r = t >> 6, c = t & 63;
        const float4* m4 = (const float4*)(meta + (r0 + r) * NMETAn);
        const float4* w4 = (const float4*)(numW + c * NMETAn);
        float acc = numb[c];
#pragma unroll
        for (int j = 0; j < 4; ++j) acc += dot4(m4[j], w4[j]);
        combs[r * 256 + 128 + c] = acc;
    } else {
        int u = t - 128, r = u >> 6, c = u & 63;
        float ca = 0.f; int cnt = 0;
#pragma unroll
        for (int k2 = 0; k2 < BAGn; ++k2) {
            int cc2 = cats[(r0 + r) * BAGn + k2];
            if (cc2 != 0) { ca += cat_w[cc2 * 64 + c]; cnt++; }
        }
        combs[r * 256 + 192 + c] = ca / (float)(cnt > 0 ? cnt : 1);
    }
    __syncthreads();

    int q = t & 3, g = t >> 2;
    // fusion GEMV (K=256), coalesced k-split, both rows share weight loads
#pragma unroll
    for (int p = 0; p < 2; ++p) {
        int h = p * 64 + g;
        const float4* w4 = (const float4*)(fusW + h * 256) + q;
        const float4* c0 = (const float4*)(combs) + q;
        const float4* c1 = (const float4*)(combs + 256) + q;
        float a0 = 0.f, a1 = 0.f;
#pragma unroll
        for (int j = 0; j < 16; ++j) {
            float4 w = w4[j * 4];
            a0 += dot4(c0[j * 4], w);
            a1 += dot4(c1[j * 4], w);
        }
        a0 = red4(a0); a1 = red4(a1);
        if (q == 0)      xs[h]       = a0 + fusb[h];
        else if (q == 1) xs[128 + h] = a1 + fusb[h];
    }
    __syncthreads();

    // embLN + keep + attnLN(0)  (round-2 verbatim)
    int w_ = t >> 6, row = w_ >> 1, l = t & 63, ch = ((w_ & 1) << 6) + l;
    float x = xs[row * 128 + ch];
    float s1 = red64(x);
    if (l == 0) wsum[w_] = s1;
    __syncthreads();
    float mean = (wsum[row * 2] + wsum[row * 2 + 1]) * (1.f / 128.f);
    float dlt = x - mean;
    float s2 = red64(dlt * dlt);
    if (l == 0) wsum[4 + w_] = s2;
    __syncthreads();
    float rstd = rsqrtf((wsum[4 + row * 2] + wsum[4 + row * 2 + 1]) * (1.f / 128.f) + EPS_EMB);
    float xv = dlt * rstd * elng[ch] + elnb[ch];
    xv = (idl[row] == 0) ? 0.f : xv;
    __syncthreads();
    xs[row * 128 + ch] = xv;
    __syncthreads();
    s1 = red64(xv);
    if (l == 0) wsum[w_] = s1;
    __syncthreads();
    mean = (wsum[row * 2] + wsum[row * 2 + 1]) * (1.f / 128.f);
    dlt = xv - mean;
    s2 = red64(dlt * dlt);
    if (l == 0) wsum[4 + w_] = s2;
    __syncthreads();
    rstd = rsqrtf((wsum[4 + row * 2] + wsum[4 + row * 2 + 1]) * (1.f / 128.f) + EPSF);
    float qn = dlt * rstd * alng[ch] + alnb[ch];
    qs[row * 128 + ch] = qn;
    Qn[(r0 + row) * 128 + ch] = qn;
    __syncthreads();

    // QKV (K=128), coalesced k-split
#pragma unroll
    for (int p = 0; p < 2; ++p) {
        int h = p * 64 + g;
        const float4* qw = (const float4*)(QW + h * 128) + q;
        const float4* kw = (const float4*)(KW + h * 128) + q;
        const float4* vw = (const float4*)(VW + h * 128) + q;
        const float4* s0p = (const float4*)(qs) + q;
        const float4* s1p = (const float4*)(qs + 128) + q;
        const float4* x0p = (const float4*)(xs) + q;
        const float4* x1p = (const float4*)(xs + 128) + q;
        float aq0 = 0, aq1 = 0, ak0 = 0, ak1 = 0, av0 = 0, av1 = 0;
#pragma unroll
        for (int j = 0; j < 8; ++j) {
            float4 wq = qw[j * 4], wk = kw[j * 4], wv = vw[j * 4];
            float4 u0 = s0p[j * 4], u1 = s1p[j * 4];
            float4 y0 = x0p[j * 4], y1 = x1p[j * 4];
            aq0 += dot4(u0, wq); aq1 += dot4(u1, wq);
            ak0 += dot4(y0, wk); ak1 += dot4(y1, wk);
            av0 += dot4(y0, wv); av1 += dot4(y1, wv);
        }
        aq0 = red4(aq0); aq1 = red4(aq1);
        ak0 = red4(ak0); ak1 = red4(ak1);
        av0 = red4(av0); av1 = red4(av1);
        if (q == 0) {
            int si = r0 & (Sn - 1);
            Q[r0 * Hn + h] = aq0 + Qb[h];
            K[r0 * Hn + h] = ak0 + Kb[h] + posK[si * Hn + h];
            V[r0 * Hn + h] = av0 + Vb[h] + posV[si * Hn + h];
        } else if (q == 1) {
            int si = (r0 + 1) & (Sn - 1);
            Q[(r0 + 1) * Hn + h] = aq1 + Qb[h];
            K[(r0 + 1) * Hn + h] = ak1 + Kb[h] + posK[si * Hn + h];
            V[(r0 + 1) * Hn + h] = av1 + Vb[h] + posV[si * Hn + h];
        }
    }
}

// ===========================================================================
// Attention (round-2 v7 VERBATIM, measured ~34us). 1024 blocks, balanced.
// ===========================================================================
static __device__ __forceinline__ void attn_phase(
    int b, int h, int i0, int t,
    const int* __restrict__ ids, const int* __restrict__ tmat,
    const float* __restrict__ Q, const float* __restrict__ K,
    const float* __restrict__ V,
    const float* __restrict__ tKw, const float* __restrict__ tVw,
    float* __restrict__ O,
    float* Kt, float* Vt, float* Stile, int* trowT,
    float* QTl, float* ql, int* tlf)
{
    if (t < 4) tlf[t] = (ids[b * Sn + i0 + t] == 0) ? 1 : 0;
    if (t < 128) {
        int q_ = t >> 5, d = t & 31;
        ql[q_ * 33 + d] = Q[(b * Sn + i0 + q_) * Hn + h * 32 + d];
    }
    __syncthreads();

    for (int tt = t; tt < Tt; tt += 256) {
        const float4* tk4 = (const float4*)(tKw + tt * Hn + h * 32);
        float a0 = 0.f, a1 = 0.f, a2 = 0.f, a3 = 0.f;
#pragma unroll
        for (int dv = 0; dv < 8; ++dv) {
            float4 w4 = tk4[dv];
            int d = dv * 4;
            a0 += ql[d] * w4.x + ql[d + 1] * w4.y + ql[d + 2] * w4.z + ql[d + 3] * w4.w;
            a1 += ql[33 + d] * w4.x + ql[34 + d] * w4.y + ql[35 + d] * w4.z + ql[36 + d] * w4.w;
            a2 += ql[66 + d] * w4.x + ql[67 + d] * w4.y + ql[68 + d] * w4.z + ql[69 + d] * w4.w;
            a3 += ql[99 + d] * w4.x + ql[100 + d] * w4.y + ql[101 + d] * w4.z + ql[102 + d] * w4.w;
        }
        QTl[tt] = a0; QTl[260 + tt] = a1; QTl[520 + tt] = a2; QTl[780 + tt] = a3;
    }

    int tl_any = tlf[0] | tlf[1] | tlf[2] | tlf[3];
    int ntiles = tl_any ? 8 : ((i0 + 3) >> 6) + 1;

    int iq = t >> 6, jj = t & 63;
    int i_g = i0 + iq;
    int my_tl = tlf[iq];
    const int* trow = tmat + (b * Sn + i_g) * Sn;

    float qreg[32];
#pragma unroll
    for (int d = 0; d < 32; ++d) qreg[d] = ql[iq * 33 + d];

    int jq = jj >> 5, d = jj & 31;
    float m = -INFINITY, lsum = 0.f, acc = 0.f;

    for (int jt = 0; jt < ntiles; ++jt) {
        int j0 = jt * 64;
        __syncthreads();
        for (int f = t; f < 64 * 8; f += 256) {
            int jl = f >> 3, dv = f & 7;
            const float* src = K + (b * Sn + j0 + jl) * Hn + h * 32 + dv * 4;
            float4 w4 = *(const float4*)src;
            float* kd = &Kt[jl * 33 + dv * 4];
            kd[0] = w4.x; kd[1] = w4.y; kd[2] = w4.z; kd[3] = w4.w;
            float4 v4 = *(const float4*)(V + (b * Sn + j0 + jl) * Hn + h * 32 + dv * 4);
            float* vd = &Vt[jl * 33 + dv * 4];
            vd[0] = v4.x; vd[1] = v4.y; vd[2] = v4.z; vd[3] = v4.w;
        }
        __syncthreads();

        int active = my_tl || (j0 <= i_g);
        if (active) {
            int j = j0 + jj;
            float sv = NEGF;
            int tv = trow[j];
            if (!my_tl && j <= i_g) {
                float a = 0.f;
#pragma unroll
                for (int dd = 0; dd < 32; ++dd)
                    a += qreg[dd] * Kt[jj * 33 + dd];
                sv = (a + QTl[iq * 260 + tv]) * INV_SQRT_D;
            }
            float mt = red64max(sv);
            float mnew = fmaxf(m, mt);
            float alpha = expf(m - mnew);
            float p = expf(sv - mnew);
            lsum = lsum * alpha + red64(p);
            m = mnew;
            acc *= alpha;
            Stile[iq * 64 + jj] = p;
            trowT[iq * 64 + jj] = tv;
        }
        __syncthreads();
        if (active) {
            int base = jq * 32;
#pragma unroll 8
            for (int jl = base; jl < base + 32; ++jl) {
                float pp = Stile[iq * 64 + jl];
                int tv2 = trowT[iq * 64 + jl];
                acc += pp * (Vt[jl * 33 + d] + tVw[tv2 * Hn + h * 32 + d]);
            }
        }
    }

    float a2 = acc + __shfl_xor(acc, 32, 64);
    if (jj < 32)
        O[(b * Sn + i_g) * Hn + h * 32 + d] = a2 / lsum;
}

__global__ __launch_bounds__(256) void attn_kernel(
    const int* ids, const int* tmat,
    const float* Q, const float* K, const float* V,
    const float* tKw, const float* tVw, float* O)
{
    __shared__ float Kt[64 * 33];
    __shared__ float Vt[64 * 33];
    __shared__ float Stile[4 * 64];
    __shared__ int   trowT[4 * 64];
    __shared__ float QTl[4 * 260];
    __shared__ float ql[4 * 33];
    __shared__ int tlf[4];
    int blk = blockIdx.x, t = threadIdx.x;
    int bh = blk & 7;
    int s  = blk >> 3;
    int g = s >> 5, r = s & 31;
    int mm;
    if      (g == 0) mm = r;
    else if (g == 1) mm = 127 - r;
    else if (g == 2) mm = 32 + r;
    else             mm = 95 - r;   // per-CU tile sum always 18
    int b = bh >> 2, h = bh & 3;
    attn_phase(b, h, mm * 4, t, ids, tmat, Q, K, V, tKw, tVw, O,
               Kt, Vt, Stile, trowT, QTl, ql, tlf);
}

// ===========================================================================
// FFN(nb) -> [attnLN(nb+1)+QKV(nb+1)] or [final LN -> out]. 2 rows/block,
// 512 blocks, all GEMVs with the coalesced 4-lane k-split.
// ===========================================================================
__global__ __launch_bounds__(256) void ffn_qkv_kernel(
    const int* __restrict__ ids, float* __restrict__ Qn,
    const float* __restrict__ O,
    const float* __restrict__ flng, const float* __restrict__ flnb,
    const float* __restrict__ w1W, const float* __restrict__ w1b,
    const float* __restrict__ w2W, const float* __restrict__ w2b,
    const float* __restrict__ alng, const float* __restrict__ alnb,
    const float* __restrict__ QW, const float* __restrict__ Qb,
    const float* __restrict__ KW, const float* __restrict__ Kb,
    const float* __restrict__ VW, const float* __restrict__ Vb,
    const float* __restrict__ posK, const float* __restrict__ posV,
    float* __restrict__ Q, float* __restrict__ K, float* __restrict__ V,
    const float* __restrict__ llng, const float* __restrict__ llnb,
    float* __restrict__ out, int nb, int last)
{
    int r0 = blockIdx.x * 2, t = threadIdx.x;
    __shared__ __align__(16) float ys[256];
    __shared__ __align__(16) float h1s[256];
    __shared__ float wsum[8];
    int id0 = ids[r0], id1 = ids[r0 + 1];

    ys[t] = Qn[r0 * 128 + t] + O[r0 * 128 + t];
    __syncthreads();
    int w_ = t >> 6, row = w_ >> 1, l = t & 63, ch = ((w_ & 1) << 6) + l;
    float x = ys[row * 128 + ch];
    float s1 = red64(x);
    if (l == 0) wsum[w_] = s1;
    __syncthreads();
    float mean = (wsum[row * 2] + wsum[row * 2 + 1]) * (1.f / 128.f);
    float dlt = x - mean;
    float s2 = red64(dlt * dlt);
    if (l == 0) wsum[4 + w_] = s2;
    __syncthreads();
    float rstd = rsqrtf((wsum[4 + row * 2] + wsum[4 + row * 2 + 1]) * (1.f / 128.f) + EPSF);
    float yv = dlt * rstd * flng[nb * 128 + ch] + flnb[nb * 128 + ch];
    __syncthreads();
    ys[row * 128 + ch] = yv;
    __syncthreads();

    int q = t & 3, g = t >> 2;
    // w1 + gelu (K=128), coalesced k-split
#pragma unroll
    for (int p = 0; p < 2; ++p) {
        int h = p * 64 + g;
        const float4* w4 = (const float4*)(w1W + nb * 16384 + h * 128) + q;
        const float4* y0 = (const float4*)(ys) + q;
        const float4* y1 = (const float4*)(ys + 128) + q;
        float a0 = 0.f, a1 = 0.f;
#pragma unroll
        for (int j = 0; j < 8; ++j) {
            float4 w = w4[j * 4];
            a0 += dot4(y0[j * 4], w);
            a1 += dot4(y1[j * 4], w);
        }
        a0 = red4(a0); a1 = red4(a1);
        if (q == 0) {
            float v0 = a0 + w1b[nb * 128 + h];
            h1s[h] = 0.5f * v0 * (1.f + erff(v0 * 0.70710678118654752f));
        } else if (q == 1) {
            float v1 = a1 + w1b[nb * 128 + h];
            h1s[128 + h] = 0.5f * v1 * (1.f + erff(v1 * 0.70710678118654752f));
        }
    }
    __syncthreads();

    // w2 + residual + keep: accumulate both passes in regs, barrier, write
    float z00, z01, z10, z11;
    {
        float zz[2][2];
#pragma unroll
        for (int p = 0; p < 2; ++p) {
            int h = p * 64 + g;
            const float4* w4 = (const float4*)(w2W + nb * 16384 + h * 128) + q;
            const float4* y0 = (const float4*)(h1s) + q;
            const float4* y1 = (const float4*)(h1s + 128) + q;
            float a0 = 0.f, a1 = 0.f;
#pragma unroll
            for (int j = 0; j < 8; ++j) {
                float4 w = w4[j * 4];
                a0 += dot4(y0[j * 4], w);
                a1 += dot4(y1[j * 4], w);
            }
            a0 = red4(a0); a1 = red4(a1);
            float b_ = w2b[nb * 128 + h];
            zz[p][0] = (id0 == 0) ? 0.f : (a0 + b_ + ys[h]);
            zz[p][1] = (id1 == 0) ? 0.f : (a1 + b_ + ys[128 + h]);
        }
        z00 = zz[0][0]; z10 = zz[1][0]; z01 = zz[0][1]; z11 = zz[1][1];
    }
    __syncthreads();               // all h1s reads done before overwrite
    if (q == 0)      { h1s[g] = z00;        h1s[64 + g] = z10; }
    else if (q == 1) { h1s[128 + g] = z01;  h1s[192 + g] = z11; }
    __syncthreads();

    if (last) {
        x = h1s[row * 128 + ch];
        s1 = red64(x);
        if (l == 0) wsum[w_] = s1;
        __syncthreads();
        mean = (wsum[row * 2] + wsum[row * 2 + 1]) * (1.f / 128.f);
        dlt = x - mean;
        s2 = red64(dlt * dlt);
        if (l == 0) wsum[4 + w_] = s2;
        __syncthreads();
        rstd = rsqrtf((wsum[4 + row * 2] + wsum[4 + row * 2 + 1]) * (1.f / 128.f) + EPSF);
        out[(r0 + row) * 128 + ch] = dlt * rstd * llng[ch] + llnb[ch];
        return;
    }

    int nq = nb + 1;
    x = h1s[row * 128 + ch];
    s1 = red64(x);
    if (l == 0) wsum[w_] = s1;
    __syncthreads();
    mean = (wsum[row * 2] + wsum[row * 2 + 1]) * (1.f / 128.f);
    dlt = x - mean;
    s2 = red64(dlt * dlt);
    if (l == 0) wsum[4 + w_] = s2;
    __syncthreads();
    rstd = rsqrtf((wsum[4 + row * 2] + wsum[4 + row * 2 + 1]) * (1.f / 128.f) + EPSF);
    float qn = dlt * rstd * alng[nq * 128 + ch] + alnb[nq * 128 + ch];
    __syncthreads();
    ys[row * 128 + ch] = qn;
    Qn[(r0 + row) * 128 + ch] = qn;
    __syncthreads();

    // QKV(nq), coalesced k-split: Q from ys(=qn), K/V from h1s(=z)
#pragma unroll
    for (int p = 0; p < 2; ++p) {
        int h = p * 64 + g;
        const float4* qw = (const float4*)(QW + nq * 16384 + h * 128) + q;
        const float4* kw = (const float4*)(KW + nq * 16384 + h * 128) + q;
        const float4* vw = (const float4*)(VW + nq * 16384 + h * 128) + q;
        const float4* s0p = (const float4*)(ys) + q;
        const float4* s1p = (const float4*)(ys + 128) + q;
        const float4* x0p = (const float4*)(h1s) + q;
        const float4* x1p = (const float4*)(h1s + 128) + q;
        float aq0 = 0, aq1 = 0, ak0 = 0, ak1 = 0, av0 = 0, av1 = 0;
#pragma unroll
        for (int j = 0; j < 8; ++j) {
            float4 wq = qw[j * 4], wk = kw[j * 4], wv = vw[j * 4];
            float4 u0 = s0p[j * 4], u1 = s1p[j * 4];
            float4 y0 = x0p[j * 4], y1 = x1p[j * 4];
            aq0 += dot4(u0, wq); aq1 += dot4(u1, wq);
            ak0 += dot4(y0, wk); ak1 += dot4(y1, wk);
            av0 += dot4(y0, wv); av1 += dot4(y1, wv);
        }
        aq0 = red4(aq0); aq1 = red4(aq1);
        ak0 = red4(ak0); ak1 = red4(ak1);
        av0 = red4(av0); av1 = red4(av1);
        if (q == 0) {
            int si = r0 & (Sn - 1);
            Q[r0 * Hn + h] = aq0 + Qb[nq * 128 + h];
            K[r0 * Hn + h] = ak0 + Kb[nq * 128 + h] + posK[si * Hn + h];
            V[r0 * Hn + h] = av0 + Vb[nq * 128 + h] + posV[si * Hn + h];
        } else if (q == 1) {
            int si = (r0 + 1) & (Sn - 1);
            Q[(r0 + 1) * Hn + h] = aq1 + Qb[nq * 128 + h];
            K[(r0 + 1) * Hn + h] = ak1 + Kb[nq * 128 + h] + posK[si * Hn + h];
            V[(r0 + 1) * Hn + h] = av1 + Vb[nq * 128 + h] + posV[si * Hn + h];
        }
    }
}

// ---------------------------------------------------------------------------
extern "C" void kernel_launch(void* const* d_in, const int* in_sizes, int n_in,
                              void* d_out, int out_size, void* d_ws, size_t ws_size,
                              hipStream_t stream) {
    const int*   ids   = (const int*)  d_in[0];
    const float* meta  = (const float*)d_in[1];
    const int*   cats  = (const int*)  d_in[2];
    const int*   tmat  = (const int*)  d_in[3];
    const float* itemw = (const float*)d_in[4];
    const float* catw  = (const float*)d_in[5];
    const float* numW  = (const float*)d_in[6];
    const float* numb  = (const float*)d_in[7];
    const float* fusW  = (const float*)d_in[8];
    const float* fusb  = (const float*)d_in[9];
    const float* elng  = (const float*)d_in[10];
    const float* elnb  = (const float*)d_in[11];
    const float* posK  = (const float*)d_in[12];
    const float* posV  = (const float*)d_in[13];
    const float* tKw   = (const float*)d_in[14];
    const float* tVw   = (const float*)d_in[15];
    const float* alng  = (const float*)d_in[16];
    const float* alnb  = (const float*)d_in[17];
    const float* QW    = (const float*)d_in[18];
    const float* Qb    = (const float*)d_in[19];
    const float* KW    = (const float*)d_in[20];
    const float* Kb    = (const float*)d_in[21];
    const float* VW    = (const float*)d_in[22];
    const float* Vb    = (const float*)d_in[23];
    const float* flng  = (const float*)d_in[24];
    const float* flnb  = (const float*)d_in[25];
    const float* w1W   = (const float*)d_in[26];
    const float* w1b   = (const float*)d_in[27];
    const float* w2W   = (const float*)d_in[28];
    const float* w2b   = (const float*)d_in[29];
    const float* llng  = (const float*)d_in[30];
    const float* llnb  = (const float*)d_in[31];
    (void)in_sizes; (void)n_in; (void)out_size; (void)ws_size;

    float* ws = (float*)d_ws;
    float* Qnp = ws + OFF_QN;
    float* Qp  = ws + OFF_Q;
    float* Kp  = ws + OFF_K;
    float* Vp  = ws + OFF_V;
    float* Op  = ws + OFF_O;
    float* outp = (float*)d_out;

    embed_qkv_kernel<<<ROWS / 2, 256, 0, stream>>>(
        ids, meta, cats, itemw, catw, numW, numb, fusW, fusb, elng, elnb,
        alng, alnb, QW, Qb, KW, Kb, VW, Vb, posK, posV, Qnp, Qp, Kp, Vp);
    for (int nb = 0; nb < NBn; ++nb) {
        attn_kernel<<<1024, 256, 0, stream>>>(ids, tmat, Qp, Kp, Vp, tKw, tVw, Op);
        ffn_qkv_kernel<<<ROWS / 2, 256, 0, stream>>>(
            ids, Qnp, Op, flng, flnb, w1W, w1b, w2W, w2b,
            alng, alnb, QW, Qb, KW, Kb, VW, Vb, posK, posV,
            Qp, Kp, Vp, llng, llnb, outp, nb, (nb == NBn - 1) ? 1 : 0);
    }
}

// Round 8
// 224.156 us; speedup vs baseline: 1.7444x; 1.0215x over previous
//
#include <hip/hip_runtime.h>
#include <math.h>

// Problem constants
#define Bn 2
#define Sn 512
#define Hn 128
#define NHn 4
#define Dn 32
#define BAGn 5
#define NMETAn 16
#define ROWS 1024
#define NBn 2
#define Tt 257

#define NEGF (-4294967295.0f)
#define INV_SQRT_D 0.17677669529663687f
#define SQRT_H 11.313708498984761f
#define EPS_EMB 1e-5f
#define EPSF 1e-8f

// workspace float offsets
#define OFF_QN    0
#define OFF_Q     131072
#define OFF_K     262144
#define OFF_V     393216
#define OFF_O     524288

static __device__ __forceinline__ float red64(float v) {
#pragma unroll
    for (int m = 1; m < 64; m <<= 1) v += __shfl_xor(v, m, 64);
    return v;
}
static __device__ __forceinline__ float red64max(float v) {
#pragma unroll
    for (int m = 1; m < 64; m <<= 1) v = fmaxf(v, __shfl_xor(v, m, 64));
    return v;
}
static __device__ __forceinline__ float dot4(float4 a, float4 b) {
    return a.x * b.x + a.y * b.y + a.z * b.z + a.w * b.w;
}
// combine partial dot across the 4-lane k-split group (all 4 lanes get sum)
static __device__ __forceinline__ float red4(float v) {
    v += __shfl_xor(v, 1, 64);
    v += __shfl_xor(v, 2, 64);
    return v;
}

// ===========================================================================
// Embed + embLN + keep + attnLN(0) + QKV(0). 2 rows/block, 512 blocks.
// All GEMVs use the coalesced 4-lane k-split (round-7, validated -35us).
// NEW (round 8): prefetch tmat/tKw/tVw slices to re-warm L2/L3 after the
// harness's 268MB workspace poison sweep (attn0's 5MB FETCH_SIZE = cold
// first-touch set) -- overlap the HBM latency with embed's compute.
// ===========================================================================
__global__ __launch_bounds__(256) void embed_qkv_kernel(
    const int* __restrict__ ids, const float* __restrict__ meta,
    const int* __restrict__ cats,
    const float* __restrict__ item_w, const float* __restrict__ cat_w,
    const float* __restrict__ numW, const float* __restrict__ numb,
    const float* __restrict__ fusW, const float* __restrict__ fusb,
    const float* __restrict__ elng, const float* __restrict__ elnb,
    const float* __restrict__ alng, const float* __restrict__ alnb,
    const float* __restrict__ QW, const float* __restrict__ Qb,
    const float* __restrict__ KW, const float* __restrict__ Kb,
    const float* __restrict__ VW, const float* __restrict__ Vb,
    const float* __restrict__ posK, const float* __restrict__ posV,
    const int* __restrict__ tmat, const float* __restrict__ tKw,
    const float* __restrict__ tVw,
    float* __restrict__ Qn, float* __restrict__ Q,
    float* __restrict__ K, float* __restrict__ V)
{
    int r0 = blockIdx.x * 2, t = threadIdx.x;
    __shared__ __align__(16) float combs[512];
    __shared__ __align__(16) float xs[256];
    __shared__ __align__(16) float qs[256];
    __shared__ float wsum[8];
    __shared__ int idl[2];

    // ---- prefetch (issue early; consumed by asm below, never stored) ----
    int pfi = 0; float pff = 0.f;
    {
        const int* tm = tmat + blockIdx.x * 1024;      // 2MB / 512 blocks
#pragma unroll
        for (int j = 0; j < 4; ++j) pfi += tm[t + j * 256];
        if (t < 64) {
            int off = blockIdx.x * 64 + t;             // 32768 of 32896
            pff = tKw[off] + tVw[off];
        } else if (blockIdx.x == 0 && t < 192) {       // tail rows
            pff = tKw[32704 + t] + tVw[32704 + t];     // 32768..32895
        }
    }

    if (t < 2) idl[t] = ids[r0 + t];
    __syncthreads();
    { int r = t >> 7, c = t & 127; combs[r * 256 + c] = item_w[idl[r] * Hn + c] * SQRT_H; }
    if (t < 128) {
        int r = t >> 6, c = t & 63;
        const float4* m4 = (const float4*)(meta + (r0 + r) * NMETAn);
        const float4* w4 = (const float4*)(numW + c * NMETAn);
        float acc = numb[c];
#pragma unroll
        for (int j = 0; j < 4; ++j) acc += dot4(m4[j], w4[j]);
        combs[r * 256 + 128 + c] = acc;
    } else {
        int u = t - 128, r = u >> 6, c = u & 63;
        float ca = 0.f; int cnt = 0;
#pragma unroll
        for (int k2 = 0; k2 < BAGn; ++k2) {
            int cc2 = cats[(r0 + r) * BAGn + k2];
            if (cc2 != 0) { ca += cat_w[cc2 * 64 + c]; cnt++; }
        }
        combs[r * 256 + 192 + c] = ca / (float)(cnt > 0 ? cnt : 1);
    }
    asm volatile("" :: "v"(pfi), "v"(pff));   // keep prefetch loads live
    __syncthreads();

    int q = t & 3, g = t >> 2;
    // fusion GEMV (K=256), coalesced k-split, both rows share weight loads
#pragma unroll
    for (int p = 0; p < 2; ++p) {
        int h = p * 64 + g;
        const float4* w4 = (const float4*)(fusW + h * 256) + q;
        const float4* c0 = (const float4*)(combs) + q;
        const float4* c1 = (const float4*)(combs + 256) + q;
        float a0 = 0.f, a1 = 0.f;
#pragma unroll
        for (int j = 0; j < 16; ++j) {
            float4 w = w4[j * 4];
            a0 += dot4(c0[j * 4], w);
            a1 += dot4(c1[j * 4], w);
        }
        a0 = red4(a0); a1 = red4(a1);
        if (q == 0)      xs[h]       = a0 + fusb[h];
        else if (q == 1) xs[128 + h] = a1 + fusb[h];
    }
    __syncthreads();

    // embLN + keep + attnLN(0)
    int w_ = t >> 6, row = w_ >> 1, l = t & 63, ch = ((w_ & 1) << 6) + l;
    float x = xs[row * 128 + ch];
    float s1 = red64(x);
    if (l == 0) wsum[w_] = s1;
    __syncthreads();
    float mean = (wsum[row * 2] + wsum[row * 2 + 1]) * (1.f / 128.f);
    float dlt = x - mean;
    float s2 = red64(dlt * dlt);
    if (l == 0) wsum[4 + w_] = s2;
    __syncthreads();
    float rstd = rsqrtf((wsum[4 + row * 2] + wsum[4 + row * 2 + 1]) * (1.f / 128.f) + EPS_EMB);
    float xv = dlt * rstd * elng[ch] + elnb[ch];
    xv = (idl[row] == 0) ? 0.f : xv;
    __syncthreads();
    xs[row * 128 + ch] = xv;
    __syncthreads();
    s1 = red64(xv);
    if (l == 0) wsum[w_] = s1;
    __syncthreads();
    mean = (wsum[row * 2] + wsum[row * 2 + 1]) * (1.f / 128.f);
    dlt = xv - mean;
    s2 = red64(dlt * dlt);
    if (l == 0) wsum[4 + w_] = s2;
    __syncthreads();
    rstd = rsqrtf((wsum[4 + row * 2] + wsum[4 + row * 2 + 1]) * (1.f / 128.f) + EPSF);
    float qn = dlt * rstd * alng[ch] + alnb[ch];
    qs[row * 128 + ch] = qn;
    Qn[(r0 + row) * 128 + ch] = qn;
    __syncthreads();

    // QKV (K=128), coalesced k-split
#pragma unroll
    for (int p = 0; p < 2; ++p) {
        int h = p * 64 + g;
        const float4* qw = (const float4*)(QW + h * 128) + q;
        const float4* kw = (const float4*)(KW + h * 128) + q;
        const float4* vw = (const float4*)(VW + h * 128) + q;
        const float4* s0p = (const float4*)(qs) + q;
        const float4* s1p = (const float4*)(qs + 128) + q;
        const float4* x0p = (const float4*)(xs) + q;
        const float4* x1p = (const float4*)(xs + 128) + q;
        float aq0 = 0, aq1 = 0, ak0 = 0, ak1 = 0, av0 = 0, av1 = 0;
#pragma unroll
        for (int j = 0; j < 8; ++j) {
            float4 wq = qw[j * 4], wk = kw[j * 4], wv = vw[j * 4];
            float4 u0 = s0p[j * 4], u1 = s1p[j * 4];
            float4 y0 = x0p[j * 4], y1 = x1p[j * 4];
            aq0 += dot4(u0, wq); aq1 += dot4(u1, wq);
            ak0 += dot4(y0, wk); ak1 += dot4(y1, wk);
            av0 += dot4(y0, wv); av1 += dot4(y1, wv);
        }
        aq0 = red4(aq0); aq1 = red4(aq1);
        ak0 = red4(ak0); ak1 = red4(ak1);
        av0 = red4(av0); av1 = red4(av1);
        if (q == 0) {
            int si = r0 & (Sn - 1);
            Q[r0 * Hn + h] = aq0 + Qb[h];
            K[r0 * Hn + h] = ak0 + Kb[h] + posK[si * Hn + h];
            V[r0 * Hn + h] = av0 + Vb[h] + posV[si * Hn + h];
        } else if (q == 1) {
            int si = (r0 + 1) & (Sn - 1);
            Q[(r0 + 1) * Hn + h] = aq1 + Qb[h];
            K[(r0 + 1) * Hn + h] = ak1 + Kb[h] + posK[si * Hn + h];
            V[(r0 + 1) * Hn + h] = av1 + Vb[h] + posV[si * Hn + h];
        }
    }
}

// ===========================================================================
// Attention: round-2 v7 + QT k-split coalescing (round 8).
// OLD QT: thread tt reads row tt -> 64 distinct 512B-apart lines per
// wave-load, each row's 128B slice touched 4x (2048 TA-cyc/block).
// NEW: lane q of group g reads float4 at dv in {q, q+4} of row c*64+g:
// 16 rows x 1 fully-used 64B line per instruction (512 TA-cyc/block),
// partials combined with red4, lane q writes accumulator q.
// ===========================================================================
static __device__ __forceinline__ void attn_phase(
    int b, int h, int i0, int t,
    const int* __restrict__ ids, const int* __restrict__ tmat,
    const float* __restrict__ Q, const float* __restrict__ K,
    const float* __restrict__ V,
    const float* __restrict__ tKw, const float* __restrict__ tVw,
    float* __restrict__ O,
    float* Kt, float* Vt, float* Stile, int* trowT,
    float* QTl, float* ql, int* tlf)
{
    if (t < 4) tlf[t] = (ids[b * Sn + i0 + t] == 0) ? 1 : 0;
    if (t < 128) {
        int q_ = t >> 5, d = t & 31;
        ql[q_ * 33 + d] = Q[(b * Sn + i0 + q_) * Hn + h * 32 + d];
    }
    __syncthreads();

    // fused QT, coalesced k-split over 4-lane groups
    {
        int qq = t & 3, gg = t >> 2;
#pragma unroll
        for (int c = 0; c < 4; ++c) {
            int tt = c * 64 + gg;
            const float4* tk4 = (const float4*)(tKw + tt * Hn + h * 32);
            float4 wA = tk4[qq];
            float4 wB = tk4[qq + 4];
            int dA = qq * 4, dB = 16 + qq * 4;
            float a0 = ql[dA]*wA.x + ql[dA+1]*wA.y + ql[dA+2]*wA.z + ql[dA+3]*wA.w
                     + ql[dB]*wB.x + ql[dB+1]*wB.y + ql[dB+2]*wB.z + ql[dB+3]*wB.w;
            float a1 = ql[33+dA]*wA.x + ql[34+dA]*wA.y + ql[35+dA]*wA.z + ql[36+dA]*wA.w
                     + ql[33+dB]*wB.x + ql[34+dB]*wB.y + ql[35+dB]*wB.z + ql[36+dB]*wB.w;
            float a2 = ql[66+dA]*wA.x + ql[67+dA]*wA.y + ql[68+dA]*wA.z + ql[69+dA]*wA.w
                     + ql[66+dB]*wB.x + ql[67+dB]*wB.y + ql[68+dB]*wB.z + ql[69+dB]*wB.w;
            float a3 = ql[99+dA]*wA.x + ql[100+dA]*wA.y + ql[101+dA]*wA.z + ql[102+dA]*wA.w
                     + ql[99+dB]*wB.x + ql[100+dB]*wB.y + ql[101+dB]*wB.z + ql[102+dB]*wB.w;
            a0 = red4(a0); a1 = red4(a1); a2 = red4(a2); a3 = red4(a3);
            if (qq == 0)      QTl[tt] = a0;
            else if (qq == 1) QTl[260 + tt] = a1;
            else if (qq == 2) QTl[520 + tt] = a2;
            else              QTl[780 + tt] = a3;
        }
        if (t < 4) {                       // row 256 (one 4-lane group)
            const float4* tk4 = (const float4*)(tKw + 256 * Hn + h * 32);
            float4 wA = tk4[t];
            float4 wB = tk4[t + 4];
            int dA = t * 4, dB = 16 + t * 4;
            float a0 = ql[dA]*wA.x + ql[dA+1]*wA.y + ql[dA+2]*wA.z + ql[dA+3]*wA.w
                     + ql[dB]*wB.x + ql[dB+1]*wB.y + ql[dB+2]*wB.z + ql[dB+3]*wB.w;
            float a1 = ql[33+dA]*wA.x + ql[34+dA]*wA.y + ql[35+dA]*wA.z + ql[36+dA]*wA.w
                     + ql[33+dB]*wB.x + ql[34+dB]*wB.y + ql[35+dB]*wB.z + ql[36+dB]*wB.w;
            float a2 = ql[66+dA]*wA.x + ql[67+dA]*wA.y + ql[68+dA]*wA.z + ql[69+dA]*wA.w
                     + ql[66+dB]*wB.x + ql[67+dB]*wB.y + ql[68+dB]*wB.z + ql[69+dB]*wB.w;
            float a3 = ql[99+dA]*wA.x + ql[100+dA]*wA.y + ql[101+dA]*wA.z + ql[102+dA]*wA.w
                     + ql[99+dB]*wB.x + ql[100+dB]*wB.y + ql[101+dB]*wB.z + ql[102+dB]*wB.w;
            a0 = red4(a0); a1 = red4(a1); a2 = red4(a2); a3 = red4(a3);
            if (t == 0)      QTl[256] = a0;
            else if (t == 1) QTl[516] = a1;
            else if (t == 2) QTl[776] = a2;
            else             QTl[1036] = a3;
        }
    }

    int tl_any = tlf[0] | tlf[1] | tlf[2] | tlf[3];
    int ntiles = tl_any ? 8 : ((i0 + 3) >> 6) + 1;

    int iq = t >> 6, jj = t & 63;
    int i_g = i0 + iq;
    int my_tl = tlf[iq];
    const int* trow = tmat + (b * Sn + i_g) * Sn;

    float qreg[32];
#pragma unroll
    for (int d = 0; d < 32; ++d) qreg[d] = ql[iq * 33 + d];

    int jq = jj >> 5, d = jj & 31;
    float m = -INFINITY, lsum = 0.f, acc = 0.f;

    for (int jt = 0; jt < ntiles; ++jt) {
        int j0 = jt * 64;
        __syncthreads();
        for (int f = t; f < 64 * 8; f += 256) {
            int jl = f >> 3, dv = f & 7;
            const float* src = K + (b * Sn + j0 + jl) * Hn + h * 32 + dv * 4;
            float4 w4 = *(const float4*)src;
            float* kd = &Kt[jl * 33 + dv * 4];
            kd[0] = w4.x; kd[1] = w4.y; kd[2] = w4.z; kd[3] = w4.w;
            float4 v4 = *(const float4*)(V + (b * Sn + j0 + jl) * Hn + h * 32 + dv * 4);
            float* vd = &Vt[jl * 33 + dv * 4];
            vd[0] = v4.x; vd[1] = v4.y; vd[2] = v4.z; vd[3] = v4.w;
        }
        __syncthreads();

        int active = my_tl || (j0 <= i_g);
        if (active) {
            int j = j0 + jj;
            float sv = NEGF;
            int tv = trow[j];
            if (!my_tl && j <= i_g) {
                float a = 0.f;
#pragma unroll
                for (int dd = 0; dd < 32; ++dd)
                    a += qreg[dd] * Kt[jj * 33 + dd];
                sv = (a + QTl[iq * 260 + tv]) * INV_SQRT_D;
            }
            float mt = red64max(sv);
            float mnew = fmaxf(m, mt);
            float alpha = expf(m - mnew);
            float p = expf(sv - mnew);
            lsum = lsum * alpha + red64(p);
            m = mnew;
            acc *= alpha;
            Stile[iq * 64 + jj] = p;
            trowT[iq * 64 + jj] = tv;
        }
        __syncthreads();
        if (active) {
            int base = jq * 32;
#pragma unroll 8
            for (int jl = base; jl < base + 32; ++jl) {
                float pp = Stile[iq * 64 + jl];
                int tv2 = trowT[iq * 64 + jl];
                acc += pp * (Vt[jl * 33 + d] + tVw[tv2 * Hn + h * 32 + d]);
            }
        }
    }

    float a2 = acc + __shfl_xor(acc, 32, 64);
    if (jj < 32)
        O[(b * Sn + i_g) * Hn + h * 32 + d] = a2 / lsum;
}

__global__ __launch_bounds__(256) void attn_kernel(
    const int* ids, const int* tmat,
    const float* Q, const float* K, const float* V,
    const float* tKw, const float* tVw, float* O)
{
    __shared__ float Kt[64 * 33];
    __shared__ float Vt[64 * 33];
    __shared__ float Stile[4 * 64];
    __shared__ int   trowT[4 * 64];
    __shared__ float QTl[4 * 260];
    __shared__ float ql[4 * 33];
    __shared__ int tlf[4];
    int blk = blockIdx.x, t = threadIdx.x;
    int bh = blk & 7;
    int s  = blk >> 3;
    int g = s >> 5, r = s & 31;
    int mm;
    if      (g == 0) mm = r;
    else if (g == 1) mm = 127 - r;
    else if (g == 2) mm = 32 + r;
    else             mm = 95 - r;   // per-CU tile sum always 18
    int b = bh >> 2, h = bh & 3;
    attn_phase(b, h, mm * 4, t, ids, tmat, Q, K, V, tKw, tVw, O,
               Kt, Vt, Stile, trowT, QTl, ql, tlf);
}

// ===========================================================================
// FFN(nb) -> [attnLN(nb+1)+QKV(nb+1)] or [final LN -> out]. 2 rows/block,
// 512 blocks, all GEMVs with the coalesced 4-lane k-split. (round-7 verbatim)
// ===========================================================================
__global__ __launch_bounds__(256) void ffn_qkv_kernel(
    const int* __restrict__ ids, float* __restrict__ Qn,
    const float* __restrict__ O,
    const float* __restrict__ flng, const float* __restrict__ flnb,
    const float* __restrict__ w1W, const float* __restrict__ w1b,
    const float* __restrict__ w2W, const float* __restrict__ w2b,
    const float* __restrict__ alng, const float* __restrict__ alnb,
    const float* __restrict__ QW, const float* __restrict__ Qb,
    const float* __restrict__ KW, const float* __restrict__ Kb,
    const float* __restrict__ VW, const float* __restrict__ Vb,
    const float* __restrict__ posK, const float* __restrict__ posV,
    float* __restrict__ Q, float* __restrict__ K, float* __restrict__ V,
    const float* __restrict__ llng, const float* __restrict__ llnb,
    float* __restrict__ out, int nb, int last)
{
    int r0 = blockIdx.x * 2, t = threadIdx.x;
    __shared__ __align__(16) float ys[256];
    __shared__ __align__(16) float h1s[256];
    __shared__ float wsum[8];
    int id0 = ids[r0], id1 = ids[r0 + 1];

    ys[t] = Qn[r0 * 128 + t] + O[r0 * 128 + t];
    __syncthreads();
    int w_ = t >> 6, row = w_ >> 1, l = t & 63, ch = ((w_ & 1) << 6) + l;
    float x = ys[row * 128 + ch];
    float s1 = red64(x);
    if (l == 0) wsum[w_] = s1;
    __syncthreads();
    float mean = (wsum[row * 2] + wsum[row * 2 + 1]) * (1.f / 128.f);
    float dlt = x - mean;
    float s2 = red64(dlt * dlt);
    if (l == 0) wsum[4 + w_] = s2;
    __syncthreads();
    float rstd = rsqrtf((wsum[4 + row * 2] + wsum[4 + row * 2 + 1]) * (1.f / 128.f) + EPSF);
    float yv = dlt * rstd * flng[nb * 128 + ch] + flnb[nb * 128 + ch];
    __syncthreads();
    ys[row * 128 + ch] = yv;
    __syncthreads();

    int q = t & 3, g = t >> 2;
    // w1 + gelu (K=128), coalesced k-split
#pragma unroll
    for (int p = 0; p < 2; ++p) {
        int h = p * 64 + g;
        const float4* w4 = (const float4*)(w1W + nb * 16384 + h * 128) + q;
        const float4* y0 = (const float4*)(ys) + q;
        const float4* y1 = (const float4*)(ys + 128) + q;
        float a0 = 0.f, a1 = 0.f;
#pragma unroll
        for (int j = 0; j < 8; ++j) {
            float4 w = w4[j * 4];
            a0 += dot4(y0[j * 4], w);
            a1 += dot4(y1[j * 4], w);
        }
        a0 = red4(a0); a1 = red4(a1);
        if (q == 0) {
            float v0 = a0 + w1b[nb * 128 + h];
            h1s[h] = 0.5f * v0 * (1.f + erff(v0 * 0.70710678118654752f));
        } else if (q == 1) {
            float v1 = a1 + w1b[nb * 128 + h];
            h1s[128 + h] = 0.5f * v1 * (1.f + erff(v1 * 0.70710678118654752f));
        }
    }
    __syncthreads();

    // w2 + residual + keep: accumulate both passes in regs, barrier, write
    float z00, z01, z10, z11;
    {
        float zz[2][2];
#pragma unroll
        for (int p = 0; p < 2; ++p) {
            int h = p * 64 + g;
            const float4* w4 = (const float4*)(w2W + nb * 16384 + h * 128) + q;
            const float4* y0 = (const float4*)(h1s) + q;
            const float4* y1 = (const float4*)(h1s + 128) + q;
            float a0 = 0.f, a1 = 0.f;
#pragma unroll
            for (int j = 0; j < 8; ++j) {
                float4 w = w4[j * 4];
                a0 += dot4(y0[j * 4], w);
                a1 += dot4(y1[j * 4], w);
            }
            a0 = red4(a0); a1 = red4(a1);
            float b_ = w2b[nb * 128 + h];
            zz[p][0] = (id0 == 0) ? 0.f : (a0 + b_ + ys[h]);
            zz[p][1] = (id1 == 0) ? 0.f : (a1 + b_ + ys[128 + h]);
        }
        z00 = zz[0][0]; z10 = zz[1][0]; z01 = zz[0][1]; z11 = zz[1][1];
    }
    __syncthreads();               // all h1s reads done before overwrite
    if (q == 0)      { h1s[g] = z00;        h1s[64 + g] = z10; }
    else if (q == 1) { h1s[128 + g] = z01;  h1s[192 + g] = z11; }
    __syncthreads();

    if (last) {
        x = h1s[row * 128 + ch];
        s1 = red64(x);
        if (l == 0) wsum[w_] = s1;
        __syncthreads();
        mean = (wsum[row * 2] + wsum[row * 2 + 1]) * (1.f / 128.f);
        dlt = x - mean;
        s2 = red64(dlt * dlt);
        if (l == 0) wsum[4 + w_] = s2;
        __syncthreads();
        rstd = rsqrtf((wsum[4 + row * 2] + wsum[4 + row * 2 + 1]) * (1.f / 128.f) + EPSF);
        out[(r0 + row) * 128 + ch] = dlt * rstd * llng[ch] + llnb[ch];
        return;
    }

    int nq = nb + 1;
    x = h1s[row * 128 + ch];
    s1 = red64(x);
    if (l == 0) wsum[w_] = s1;
    __syncthreads();
    mean = (wsum[row * 2] + wsum[row * 2 + 1]) * (1.f / 128.f);
    dlt = x - mean;
    s2 = red64(dlt * dlt);
    if (l == 0) wsum[4 + w_] = s2;
    __syncthreads();
    rstd = rsqrtf((wsum[4 + row * 2] + wsum[4 + row * 2 + 1]) * (1.f / 128.f) + EPSF);
    float qn = dlt * rstd * alng[nq * 128 + ch] + alnb[nq * 128 + ch];
    __syncthreads();
    ys[row * 128 + ch] = qn;
    Qn[(r0 + row) * 128 + ch] = qn;
    __syncthreads();

    // QKV(nq), coalesced k-split: Q from ys(=qn), K/V from h1s(=z)
#pragma unroll
    for (int p = 0; p < 2; ++p) {
        int h = p * 64 + g;
        const float4* qw = (const float4*)(QW + nq * 16384 + h * 128) + q;
        const float4* kw = (const float4*)(KW + nq * 16384 + h * 128) + q;
        const float4* vw = (const float4*)(VW + nq * 16384 + h * 128) + q;
        const float4* s0p = (const float4*)(ys) + q;
        const float4* s1p = (const float4*)(ys + 128) + q;
        const float4* x0p = (const float4*)(h1s) + q;
        const float4* x1p = (const float4*)(h1s + 128) + q;
        float aq0 = 0, aq1 = 0, ak0 = 0, ak1 = 0, av0 = 0, av1 = 0;
#pragma unroll
        for (int j = 0; j < 8; ++j) {
            float4 wq = qw[j * 4], wk = kw[j * 4], wv = vw[j * 4];
            float4 u0 = s0p[j * 4], u1 = s1p[j * 4];
            float4 y0 = x0p[j * 4], y1 = x1p[j * 4];
            aq0 += dot4(u0, wq); aq1 += dot4(u1, wq);
            ak0 += dot4(y0, wk); ak1 += dot4(y1, wk);
            av0 += dot4(y0, wv); av1 += dot4(y1, wv);
        }
        aq0 = red4(aq0); aq1 = red4(aq1);
        ak0 = red4(ak0); ak1 = red4(ak1);
        av0 = red4(av0); av1 = red4(av1);
        if (q == 0) {
            int si = r0 & (Sn - 1);
            Q[r0 * Hn + h] = aq0 + Qb[nq * 128 + h];
            K[r0 * Hn + h] = ak0 + Kb[nq * 128 + h] + posK[si * Hn + h];
            V[r0 * Hn + h] = av0 + Vb[nq * 128 + h] + posV[si * Hn + h];
        } else if (q == 1) {
            int si = (r0 + 1) & (Sn - 1);
            Q[(r0 + 1) * Hn + h] = aq1 + Qb[nq * 128 + h];
            K[(r0 + 1) * Hn + h] = ak1 + Kb[nq * 128 + h] + posK[si * Hn + h];
            V[(r0 + 1) * Hn + h] = av1 + Vb[nq * 128 + h] + posV[si * Hn + h];
        }
    }
}

// ---------------------------------------------------------------------------
extern "C" void kernel_launch(void* const* d_in, const int* in_sizes, int n_in,
                              void* d_out, int out_size, void* d_ws, size_t ws_size,
                              hipStream_t stream) {
    const int*   ids   = (const int*)  d_in[0];
    const float* meta  = (const float*)d_in[1];
    const int*   cats  = (const int*)  d_in[2];
    const int*   tmat  = (const int*)  d_in[3];
    const float* itemw = (const float*)d_in[4];
    const float* catw  = (const float*)d_in[5];
    const float* numW  = (const float*)d_in[6];
    const float* numb  = (const float*)d_in[7];
    const float* fusW  = (const float*)d_in[8];
    const float* fusb  = (const float*)d_in[9];
    const float* elng  = (const float*)d_in[10];
    const float* elnb  = (const float*)d_in[11];
    const float* posK  = (const float*)d_in[12];
    const float* posV  = (const float*)d_in[13];
    const float* tKw   = (const float*)d_in[14];
    const float* tVw   = (const float*)d_in[15];
    const float* alng  = (const float*)d_in[16];
    const float* alnb  = (const float*)d_in[17];
    const float* QW    = (const float*)d_in[18];
    const float* Qb    = (const float*)d_in[19];
    const float* KW    = (const float*)d_in[20];
    const float* Kb    = (const float*)d_in[21];
    const float* VW    = (const float*)d_in[22];
    const float* Vb    = (const float*)d_in[23];
    const float* flng  = (const float*)d_in[24];
    const float* flnb  = (const float*)d_in[25];
    const float* w1W   = (const float*)d_in[26];
    const float* w1b   = (const float*)d_in[27];
    const float* w2W   = (const float*)d_in[28];
    const float* w2b   = (const float*)d_in[29];
    const float* llng  = (const float*)d_in[30];
    const float* llnb  = (const float*)d_in[31];
    (void)in_sizes; (void)n_in; (void)out_size; (void)ws_size;

    float* ws = (float*)d_ws;
    float* Qnp = ws + OFF_QN;
    float* Qp  = ws + OFF_Q;
    float* Kp  = ws + OFF_K;
    float* Vp  = ws + OFF_V;
    float* Op  = ws + OFF_O;
    float* outp = (float*)d_out;

    embed_qkv_kernel<<<ROWS / 2, 256, 0, stream>>>(
        ids, meta, cats, itemw, catw, numW, numb, fusW, fusb, elng, elnb,
        alng, alnb, QW, Qb, KW, Kb, VW, Vb, posK, posV, tmat, tKw, tVw,
        Qnp, Qp, Kp, Vp);
    for (int nb = 0; nb < NBn; ++nb) {
        attn_kernel<<<1024, 256, 0, stream>>>(ids, tmat, Qp, Kp, Vp, tKw, tVw, Op);
        ffn_qkv_kernel<<<ROWS / 2, 256, 0, stream>>>(
            ids, Qnp, Op, flng, flnb, w1W, w1b, w2W, w2b,
            alng, alnb, QW, Qb, KW, Kb, VW, Vb, posK, posV,
            Qp, Kp, Vp, llng, llnb, outp, nb, (nb == NBn - 1) ? 1 : 0);
    }
}

// Round 9
// 219.698 us; speedup vs baseline: 1.7798x; 1.0203x over previous
//
#include <hip/hip_runtime.h>
#include <math.h>

// Problem constants
#define Bn 2
#define Sn 512
#define Hn 128
#define NHn 4
#define Dn 32
#define BAGn 5
#define NMETAn 16
#define ROWS 1024
#define NBn 2
#define Tt 257

#define NEGF (-4294967295.0f)
#define INV_SQRT_D 0.17677669529663687f
#define SQRT_H 11.313708498984761f
#define EPS_EMB 1e-5f
#define EPSF 1e-8f

// workspace float offsets
#define OFF_QN    0
#define OFF_Q     131072
#define OFF_K     262144
#define OFF_V     393216
#define OFF_O     524288

static __device__ __forceinline__ float red64(float v) {
#pragma unroll
    for (int m = 1; m < 64; m <<= 1) v += __shfl_xor(v, m, 64);
    return v;
}
static __device__ __forceinline__ float red64max(float v) {
#pragma unroll
    for (int m = 1; m < 64; m <<= 1) v = fmaxf(v, __shfl_xor(v, m, 64));
    return v;
}
static __device__ __forceinline__ float dot4(float4 a, float4 b) {
    return a.x * b.x + a.y * b.y + a.z * b.z + a.w * b.w;
}
// combine partial dot across the 4-lane k-split group (all 4 lanes get sum)
static __device__ __forceinline__ float red4(float v) {
    v += __shfl_xor(v, 1, 64);
    v += __shfl_xor(v, 2, 64);
    return v;
}

// ===========================================================================
// Embed + embLN + keep + attnLN(0) + QKV(0). 2 rows/block, 512 blocks.
// Coalesced k-split GEMVs (round 7) + tmat/tKw/tVw L2-rewarm prefetch (r8).
// ===========================================================================
__global__ __launch_bounds__(256) void embed_qkv_kernel(
    const int* __restrict__ ids, const float* __restrict__ meta,
    const int* __restrict__ cats,
    const float* __restrict__ item_w, const float* __restrict__ cat_w,
    const float* __restrict__ numW, const float* __restrict__ numb,
    const float* __restrict__ fusW, const float* __restrict__ fusb,
    const float* __restrict__ elng, const float* __restrict__ elnb,
    const float* __restrict__ alng, const float* __restrict__ alnb,
    const float* __restrict__ QW, const float* __restrict__ Qb,
    const float* __restrict__ KW, const float* __restrict__ Kb,
    const float* __restrict__ VW, const float* __restrict__ Vb,
    const float* __restrict__ posK, const float* __restrict__ posV,
    const int* __restrict__ tmat, const float* __restrict__ tKw,
    const float* __restrict__ tVw,
    float* __restrict__ Qn, float* __restrict__ Q,
    float* __restrict__ K, float* __restrict__ V)
{
    int r0 = blockIdx.x * 2, t = threadIdx.x;
    __shared__ __align__(16) float combs[512];
    __shared__ __align__(16) float xs[256];
    __shared__ __align__(16) float qs[256];
    __shared__ float wsum[8];
    __shared__ int idl[2];

    // ---- prefetch (issue early; consumed by asm below, never stored) ----
    int pfi = 0; float pff = 0.f;
    {
        const int* tm = tmat + blockIdx.x * 1024;      // 2MB / 512 blocks
#pragma unroll
        for (int j = 0; j < 4; ++j) pfi += tm[t + j * 256];
        if (t < 64) {
            int off = blockIdx.x * 64 + t;             // 32768 of 32896
            pff = tKw[off] + tVw[off];
        } else if (blockIdx.x == 0 && t < 192) {       // tail rows
            pff = tKw[32704 + t] + tVw[32704 + t];     // 32768..32895
        }
    }

    if (t < 2) idl[t] = ids[r0 + t];
    __syncthreads();
    { int r = t >> 7, c = t & 127; combs[r * 256 + c] = item_w[idl[r] * Hn + c] * SQRT_H; }
    if (t < 128) {
        int r = t >> 6, c = t & 63;
        const float4* m4 = (const float4*)(meta + (r0 + r) * NMETAn);
        const float4* w4 = (const float4*)(numW + c * NMETAn);
        float acc = numb[c];
#pragma unroll
        for (int j = 0; j < 4; ++j) acc += dot4(m4[j], w4[j]);
        combs[r * 256 + 128 + c] = acc;
    } else {
        int u = t - 128, r = u >> 6, c = u & 63;
        float ca = 0.f; int cnt = 0;
#pragma unroll
        for (int k2 = 0; k2 < BAGn; ++k2) {
            int cc2 = cats[(r0 + r) * BAGn + k2];
            if (cc2 != 0) { ca += cat_w[cc2 * 64 + c]; cnt++; }
        }
        combs[r * 256 + 192 + c] = ca / (float)(cnt > 0 ? cnt : 1);
    }
    asm volatile("" :: "v"(pfi), "v"(pff));   // keep prefetch loads live
    __syncthreads();

    int q = t & 3, g = t >> 2;
    // fusion GEMV (K=256), coalesced k-split, both rows share weight loads
#pragma unroll
    for (int p = 0; p < 2; ++p) {
        int h = p * 64 + g;
        const float4* w4 = (const float4*)(fusW + h * 256) + q;
        const float4* c0 = (const float4*)(combs) + q;
        const float4* c1 = (const float4*)(combs + 256) + q;
        float a0 = 0.f, a1 = 0.f;
#pragma unroll
        for (int j = 0; j < 16; ++j) {
            float4 w = w4[j * 4];
            a0 += dot4(c0[j * 4], w);
            a1 += dot4(c1[j * 4], w);
        }
        a0 = red4(a0); a1 = red4(a1);
        if (q == 0)      xs[h]       = a0 + fusb[h];
        else if (q == 1) xs[128 + h] = a1 + fusb[h];
    }
    __syncthreads();

    // embLN + keep + attnLN(0)
    int w_ = t >> 6, row = w_ >> 1, l = t & 63, ch = ((w_ & 1) << 6) + l;
    float x = xs[row * 128 + ch];
    float s1 = red64(x);
    if (l == 0) wsum[w_] = s1;
    __syncthreads();
    float mean = (wsum[row * 2] + wsum[row * 2 + 1]) * (1.f / 128.f);
    float dlt = x - mean;
    float s2 = red64(dlt * dlt);
    if (l == 0) wsum[4 + w_] = s2;
    __syncthreads();
    float rstd = rsqrtf((wsum[4 + row * 2] + wsum[4 + row * 2 + 1]) * (1.f / 128.f) + EPS_EMB);
    float xv = dlt * rstd * elng[ch] + elnb[ch];
    xv = (idl[row] == 0) ? 0.f : xv;
    __syncthreads();
    xs[row * 128 + ch] = xv;
    __syncthreads();
    s1 = red64(xv);
    if (l == 0) wsum[w_] = s1;
    __syncthreads();
    mean = (wsum[row * 2] + wsum[row * 2 + 1]) * (1.f / 128.f);
    dlt = xv - mean;
    s2 = red64(dlt * dlt);
    if (l == 0) wsum[4 + w_] = s2;
    __syncthreads();
    rstd = rsqrtf((wsum[4 + row * 2] + wsum[4 + row * 2 + 1]) * (1.f / 128.f) + EPSF);
    float qn = dlt * rstd * alng[ch] + alnb[ch];
    qs[row * 128 + ch] = qn;
    Qn[(r0 + row) * 128 + ch] = qn;
    __syncthreads();

    // QKV (K=128), coalesced k-split
#pragma unroll
    for (int p = 0; p < 2; ++p) {
        int h = p * 64 + g;
        const float4* qw = (const float4*)(QW + h * 128) + q;
        const float4* kw = (const float4*)(KW + h * 128) + q;
        const float4* vw = (const float4*)(VW + h * 128) + q;
        const float4* s0p = (const float4*)(qs) + q;
        const float4* s1p = (const float4*)(qs + 128) + q;
        const float4* x0p = (const float4*)(xs) + q;
        const float4* x1p = (const float4*)(xs + 128) + q;
        float aq0 = 0, aq1 = 0, ak0 = 0, ak1 = 0, av0 = 0, av1 = 0;
#pragma unroll
        for (int j = 0; j < 8; ++j) {
            float4 wq = qw[j * 4], wk = kw[j * 4], wv = vw[j * 4];
            float4 u0 = s0p[j * 4], u1 = s1p[j * 4];
            float4 y0 = x0p[j * 4], y1 = x1p[j * 4];
            aq0 += dot4(u0, wq); aq1 += dot4(u1, wq);
            ak0 += dot4(y0, wk); ak1 += dot4(y1, wk);
            av0 += dot4(y0, wv); av1 += dot4(y1, wv);
        }
        aq0 = red4(aq0); aq1 = red4(aq1);
        ak0 = red4(ak0); ak1 = red4(ak1);
        av0 = red4(av0); av1 = red4(av1);
        if (q == 0) {
            int si = r0 & (Sn - 1);
            Q[r0 * Hn + h] = aq0 + Qb[h];
            K[r0 * Hn + h] = ak0 + Kb[h] + posK[si * Hn + h];
            V[r0 * Hn + h] = av0 + Vb[h] + posV[si * Hn + h];
        } else if (q == 1) {
            int si = (r0 + 1) & (Sn - 1);
            Q[(r0 + 1) * Hn + h] = aq1 + Qb[h];
            K[(r0 + 1) * Hn + h] = ak1 + Kb[h] + posK[si * Hn + h];
            V[(r0 + 1) * Hn + h] = av1 + Vb[h] + posV[si * Hn + h];
        }
    }
}

// ===========================================================================
// Attention round 9: (a) Kt/Vt/ql stride 33 -> 36 floats (144B rows, 16B
// aligned): score-row reads become 8x ds_read_b128 instead of 32x b32 (bank
// pattern (9*jj+k) mod 32, 9 odd -> bijective, conflict-free); staging
// writes become float4. (b) mid-tile barrier DROPPED: Stile/trowT are
// written and read by the SAME wave (wave iq owns [iq*64+*]) -- same-wave
// LDS RAW is ordered by lgkmcnt, no barrier needed; 3 -> 2 barriers/tile.
// ===========================================================================
static __device__ __forceinline__ void attn_phase(
    int b, int h, int i0, int t,
    const int* __restrict__ ids, const int* __restrict__ tmat,
    const float* __restrict__ Q, const float* __restrict__ K,
    const float* __restrict__ V,
    const float* __restrict__ tKw, const float* __restrict__ tVw,
    float* __restrict__ O,
    float* Kt, float* Vt, float* Stile, int* trowT,
    float* QTl, float* ql, int* tlf)
{
    if (t < 4) tlf[t] = (ids[b * Sn + i0 + t] == 0) ? 1 : 0;
    if (t < 128) {
        int q_ = t >> 5, d = t & 31;
        ql[q_ * 36 + d] = Q[(b * Sn + i0 + q_) * Hn + h * 32 + d];
    }
    __syncthreads();

    // fused QT, coalesced k-split over 4-lane groups (ql stride 36)
    {
        int qq = t & 3, gg = t >> 2;
#pragma unroll
        for (int c = 0; c < 4; ++c) {
            int tt = c * 64 + gg;
            const float4* tk4 = (const float4*)(tKw + tt * Hn + h * 32);
            float4 wA = tk4[qq];
            float4 wB = tk4[qq + 4];
            int dA = qq * 4, dB = 16 + qq * 4;
            float a0 = ql[dA]*wA.x + ql[dA+1]*wA.y + ql[dA+2]*wA.z + ql[dA+3]*wA.w
                     + ql[dB]*wB.x + ql[dB+1]*wB.y + ql[dB+2]*wB.z + ql[dB+3]*wB.w;
            float a1 = ql[36+dA]*wA.x + ql[37+dA]*wA.y + ql[38+dA]*wA.z + ql[39+dA]*wA.w
                     + ql[36+dB]*wB.x + ql[37+dB]*wB.y + ql[38+dB]*wB.z + ql[39+dB]*wB.w;
            float a2 = ql[72+dA]*wA.x + ql[73+dA]*wA.y + ql[74+dA]*wA.z + ql[75+dA]*wA.w
                     + ql[72+dB]*wB.x + ql[73+dB]*wB.y + ql[74+dB]*wB.z + ql[75+dB]*wB.w;
            float a3 = ql[108+dA]*wA.x + ql[109+dA]*wA.y + ql[110+dA]*wA.z + ql[111+dA]*wA.w
                     + ql[108+dB]*wB.x + ql[109+dB]*wB.y + ql[110+dB]*wB.z + ql[111+dB]*wB.w;
            a0 = red4(a0); a1 = red4(a1); a2 = red4(a2); a3 = red4(a3);
            if (qq == 0)      QTl[tt] = a0;
            else if (qq == 1) QTl[260 + tt] = a1;
            else if (qq == 2) QTl[520 + tt] = a2;
            else              QTl[780 + tt] = a3;
        }
        if (t < 4) {                       // row 256 (one 4-lane group)
            const float4* tk4 = (const float4*)(tKw + 256 * Hn + h * 32);
            float4 wA = tk4[t];
            float4 wB = tk4[t + 4];
            int dA = t * 4, dB = 16 + t * 4;
            float a0 = ql[dA]*wA.x + ql[dA+1]*wA.y + ql[dA+2]*wA.z + ql[dA+3]*wA.w
                     + ql[dB]*wB.x + ql[dB+1]*wB.y + ql[dB+2]*wB.z + ql[dB+3]*wB.w;
            float a1 = ql[36+dA]*wA.x + ql[37+dA]*wA.y + ql[38+dA]*wA.z + ql[39+dA]*wA.w
                     + ql[36+dB]*wB.x + ql[37+dB]*wB.y + ql[38+dB]*wB.z + ql[39+dB]*wB.w;
            float a2 = ql[72+dA]*wA.x + ql[73+dA]*wA.y + ql[74+dA]*wA.z + ql[75+dA]*wA.w
                     + ql[72+dB]*wB.x + ql[73+dB]*wB.y + ql[74+dB]*wB.z + ql[75+dB]*wB.w;
            float a3 = ql[108+dA]*wA.x + ql[109+dA]*wA.y + ql[110+dA]*wA.z + ql[111+dA]*wA.w
                     + ql[108+dB]*wB.x + ql[109+dB]*wB.y + ql[110+dB]*wB.z + ql[111+dB]*wB.w;
            a0 = red4(a0); a1 = red4(a1); a2 = red4(a2); a3 = red4(a3);
            if (t == 0)      QTl[256] = a0;
            else if (t == 1) QTl[516] = a1;
            else if (t == 2) QTl[776] = a2;
            else             QTl[1036] = a3;
        }
    }

    int tl_any = tlf[0] | tlf[1] | tlf[2] | tlf[3];
    int ntiles = tl_any ? 8 : ((i0 + 3) >> 6) + 1;

    int iq = t >> 6, jj = t & 63;
    int i_g = i0 + iq;
    int my_tl = tlf[iq];
    const int* trow = tmat + (b * Sn + i_g) * Sn;

    float4 qv[8];
    {
        const float4* qp = (const float4*)(ql + iq * 36);
#pragma unroll
        for (int d = 0; d < 8; ++d) qv[d] = qp[d];
    }

    int jq = jj >> 5, d = jj & 31;
    float m = -INFINITY, lsum = 0.f, acc = 0.f;

    for (int jt = 0; jt < ntiles; ++jt) {
        int j0 = jt * 64;
        __syncthreads();           // prior PV done before re-staging
        for (int f = t; f < 64 * 8; f += 256) {
            int jl = f >> 3, dv = f & 7;
            float4 w4 = *(const float4*)(K + (b * Sn + j0 + jl) * Hn + h * 32 + dv * 4);
            *(float4*)(Kt + jl * 36 + dv * 4) = w4;
            float4 v4 = *(const float4*)(V + (b * Sn + j0 + jl) * Hn + h * 32 + dv * 4);
            *(float4*)(Vt + jl * 36 + dv * 4) = v4;
        }
        __syncthreads();

        int active = my_tl || (j0 <= i_g);   // wave-uniform
        if (active) {
            int j = j0 + jj;
            float sv = NEGF;
            int tv = trow[j];
            if (!my_tl && j <= i_g) {
                const float4* kr = (const float4*)(Kt + jj * 36);
                float a = 0.f;
#pragma unroll
                for (int dd = 0; dd < 8; ++dd)
                    a += dot4(qv[dd], kr[dd]);
                sv = (a + QTl[iq * 260 + tv]) * INV_SQRT_D;
            }
            float mt = red64max(sv);
            float mnew = fmaxf(m, mt);
            float alpha = expf(m - mnew);    // m=-inf first tile -> 0
            float p = expf(sv - mnew);
            lsum = lsum * alpha + red64(p);
            m = mnew;
            acc *= alpha;
            Stile[iq * 64 + jj] = p;
            trowT[iq * 64 + jj] = tv;
            // no barrier: Stile/trowT are same-wave private (lgkmcnt orders)
            int base = jq * 32;
#pragma unroll 8
            for (int jl = base; jl < base + 32; ++jl) {
                float pp = Stile[iq * 64 + jl];
                int tv2 = trowT[iq * 64 + jl];
                acc += pp * (Vt[jl * 36 + d] + tVw[tv2 * Hn + h * 32 + d]);
            }
        }
    }

    // finalize: sum the two jq halves, divide by l
    float a2 = acc + __shfl_xor(acc, 32, 64);
    if (jj < 32)
        O[(b * Sn + i_g) * Hn + h * 32 + d] = a2 / lsum;
}

__global__ __launch_bounds__(256) void attn_kernel(
    const int* ids, const int* tmat,
    const float* Q, const float* K, const float* V,
    const float* tKw, const float* tVw, float* O)
{
    __shared__ __align__(16) float Kt[64 * 36];
    __shared__ __align__(16) float Vt[64 * 36];
    __shared__ float Stile[4 * 64];
    __shared__ int   trowT[4 * 64];
    __shared__ float QTl[4 * 260];
    __shared__ __align__(16) float ql[4 * 36];
    __shared__ int tlf[4];
    int blk = blockIdx.x, t = threadIdx.x;
    int bh = blk & 7;
    int s  = blk >> 3;
    int g = s >> 5, r = s & 31;
    int mm;
    if      (g == 0) mm = r;
    else if (g == 1) mm = 127 - r;
    else if (g == 2) mm = 32 + r;
    else             mm = 95 - r;   // per-CU tile sum always 18
    int b = bh >> 2, h = bh & 3;
    attn_phase(b, h, mm * 4, t, ids, tmat, Q, K, V, tKw, tVw, O,
               Kt, Vt, Stile, trowT, QTl, ql, tlf);
}

// ===========================================================================
// FFN(nb) -> [attnLN(nb+1)+QKV(nb+1)] or [final LN -> out]. 2 rows/block,
// 512 blocks, all GEMVs with the coalesced 4-lane k-split. (round-7 verbatim)
// ===========================================================================
__global__ __launch_bounds__(256) void ffn_qkv_kernel(
    const int* __restrict__ ids, float* __restrict__ Qn,
    const float* __restrict__ O,
    const float* __restrict__ flng, const float* __restrict__ flnb,
    const float* __restrict__ w1W, const float* __restrict__ w1b,
    const float* __restrict__ w2W, const float* __restrict__ w2b,
    const float* __restrict__ alng, const float* __restrict__ alnb,
    const float* __restrict__ QW, const float* __restrict__ Qb,
    const float* __restrict__ KW, const float* __restrict__ Kb,
    const float* __restrict__ VW, const float* __restrict__ Vb,
    const float* __restrict__ posK, const float* __restrict__ posV,
    float* __restrict__ Q, float* __restrict__ K, float* __restrict__ V,
    const float* __restrict__ llng, const float* __restrict__ llnb,
    float* __restrict__ out, int nb, int last)
{
    int r0 = blockIdx.x * 2, t = threadIdx.x;
    __shared__ __align__(16) float ys[256];
    __shared__ __align__(16) float h1s[256];
    __shared__ float wsum[8];
    int id0 = ids[r0], id1 = ids[r0 + 1];

    ys[t] = Qn[r0 * 128 + t] + O[r0 * 128 + t];
    __syncthreads();
    int w_ = t >> 6, row = w_ >> 1, l = t & 63, ch = ((w_ & 1) << 6) + l;
    float x = ys[row * 128 + ch];
    float s1 = red64(x);
    if (l == 0) wsum[w_] = s1;
    __syncthreads();
    float mean = (wsum[row * 2] + wsum[row * 2 + 1]) * (1.f / 128.f);
    float dlt = x - mean;
    float s2 = red64(dlt * dlt);
    if (l == 0) wsum[4 + w_] = s2;
    __syncthreads();
    float rstd = rsqrtf((wsum[4 + row * 2] + wsum[4 + row * 2 + 1]) * (1.f / 128.f) + EPSF);
    float yv = dlt * rstd * flng[nb * 128 + ch] + flnb[nb * 128 + ch];
    __syncthreads();
    ys[row * 128 + ch] = yv;
    __syncthreads();

    int q = t & 3, g = t >> 2;
    // w1 + gelu (K=128), coalesced k-split
#pragma unroll
    for (int p = 0; p < 2; ++p) {
        int h = p * 64 + g;
        const float4* w4 = (const float4*)(w1W + nb * 16384 + h * 128) + q;
        const float4* y0 = (const float4*)(ys) + q;
        const float4* y1 = (const float4*)(ys + 128) + q;
        float a0 = 0.f, a1 = 0.f;
#pragma unroll
        for (int j = 0; j < 8; ++j) {
            float4 w = w4[j * 4];
            a0 += dot4(y0[j * 4], w);
            a1 += dot4(y1[j * 4], w);
        }
        a0 = red4(a0); a1 = red4(a1);
        if (q == 0) {
            float v0 = a0 + w1b[nb * 128 + h];
            h1s[h] = 0.5f * v0 * (1.f + erff(v0 * 0.70710678118654752f));
        } else if (q == 1) {
            float v1 = a1 + w1b[nb * 128 + h];
            h1s[128 + h] = 0.5f * v1 * (1.f + erff(v1 * 0.70710678118654752f));
        }
    }
    __syncthreads();

    // w2 + residual + keep: accumulate both passes in regs, barrier, write
    float z00, z01, z10, z11;
    {
        float zz[2][2];
#pragma unroll
        for (int p = 0; p < 2; ++p) {
            int h = p * 64 + g;
            const float4* w4 = (const float4*)(w2W + nb * 16384 + h * 128) + q;
            const float4* y0 = (const float4*)(h1s) + q;
            const float4* y1 = (const float4*)(h1s + 128) + q;
            float a0 = 0.f, a1 = 0.f;
#pragma unroll
            for (int j = 0; j < 8; ++j) {
                float4 w = w4[j * 4];
                a0 += dot4(y0[j * 4], w);
                a1 += dot4(y1[j * 4], w);
            }
            a0 = red4(a0); a1 = red4(a1);
            float b_ = w2b[nb * 128 + h];
            zz[p][0] = (id0 == 0) ? 0.f : (a0 + b_ + ys[h]);
            zz[p][1] = (id1 == 0) ? 0.f : (a1 + b_ + ys[128 + h]);
        }
        z00 = zz[0][0]; z10 = zz[1][0]; z01 = zz[0][1]; z11 = zz[1][1];
    }
    __syncthreads();               // all h1s reads done before overwrite
    if (q == 0)      { h1s[g] = z00;        h1s[64 + g] = z10; }
    else if (q == 1) { h1s[128 + g] = z01;  h1s[192 + g] = z11; }
    __syncthreads();

    if (last) {
        x = h1s[row * 128 + ch];
        s1 = red64(x);
        if (l == 0) wsum[w_] = s1;
        __syncthreads();
        mean = (wsum[row * 2] + wsum[row * 2 + 1]) * (1.f / 128.f);
        dlt = x - mean;
        s2 = red64(dlt * dlt);
        if (l == 0) wsum[4 + w_] = s2;
        __syncthreads();
        rstd = rsqrtf((wsum[4 + row * 2] + wsum[4 + row * 2 + 1]) * (1.f / 128.f) + EPSF);
        out[(r0 + row) * 128 + ch] = dlt * rstd * llng[ch] + llnb[ch];
        return;
    }

    int nq = nb + 1;
    x = h1s[row * 128 + ch];
    s1 = red64(x);
    if (l == 0) wsum[w_] = s1;
    __syncthreads();
    mean = (wsum[row * 2] + wsum[row * 2 + 1]) * (1.f / 128.f);
    dlt = x - mean;
    s2 = red64(dlt * dlt);
    if (l == 0) wsum[4 + w_] = s2;
    __syncthreads();
    rstd = rsqrtf((wsum[4 + row * 2] + wsum[4 + row * 2 + 1]) * (1.f / 128.f) + EPSF);
    float qn = dlt * rstd * alng[nq * 128 + ch] + alnb[nq * 128 + ch];
    __syncthreads();
    ys[row * 128 + ch] = qn;
    Qn[(r0 + row) * 128 + ch] = qn;
    __syncthreads();

    // QKV(nq), coalesced k-split: Q from ys(=qn), K/V from h1s(=z)
#pragma unroll
    for (int p = 0; p < 2; ++p) {
        int h = p * 64 + g;
        const float4* qw = (const float4*)(QW + nq * 16384 + h * 128) + q;
        const float4* kw = (const float4*)(KW + nq * 16384 + h * 128) + q;
        const float4* vw = (const float4*)(VW + nq * 16384 + h * 128) + q;
        const float4* s0p = (const float4*)(ys) + q;
        const float4* s1p = (const float4*)(ys + 128) + q;
        const float4* x0p = (const float4*)(h1s) + q;
        const float4* x1p = (const float4*)(h1s + 128) + q;
        float aq0 = 0, aq1 = 0, ak0 = 0, ak1 = 0, av0 = 0, av1 = 0;
#pragma unroll
        for (int j = 0; j < 8; ++j) {
            float4 wq = qw[j * 4], wk = kw[j * 4], wv = vw[j * 4];
            float4 u0 = s0p[j * 4], u1 = s1p[j * 4];
            float4 y0 = x0p[j * 4], y1 = x1p[j * 4];
            aq0 += dot4(u0, wq); aq1 += dot4(u1, wq);
            ak0 += dot4(y0, wk); ak1 += dot4(y1, wk);
            av0 += dot4(y0, wv); av1 += dot4(y1, wv);
        }
        aq0 = red4(aq0); aq1 = red4(aq1);
        ak0 = red4(ak0); ak1 = red4(ak1);
        av0 = red4(av0); av1 = red4(av1);
        if (q == 0) {
            int si = r0 & (Sn - 1);
            Q[r0 * Hn + h] = aq0 + Qb[nq * 128 + h];
            K[r0 * Hn + h] = ak0 + Kb[nq * 128 + h] + posK[si * Hn + h];
            V[r0 * Hn + h] = av0 + Vb[nq * 128 + h] + posV[si * Hn + h];
        } else if (q == 1) {
            int si = (r0 + 1) & (Sn - 1);
            Q[(r0 + 1) * Hn + h] = aq1 + Qb[nq * 128 + h];
            K[(r0 + 1) * Hn + h] = ak1 + Kb[nq * 128 + h] + posK[si * Hn + h];
            V[(r0 + 1) * Hn + h] = av1 + Vb[nq * 128 + h] + posV[si * Hn + h];
        }
    }
}

// ---------------------------------------------------------------------------
extern "C" void kernel_launch(void* const* d_in, const int* in_sizes, int n_in,
                              void* d_out, int out_size, void* d_ws, size_t ws_size,
                              hipStream_t stream) {
    const int*   ids   = (const int*)  d_in[0];
    const float* meta  = (const float*)d_in[1];
    const int*   cats  = (const int*)  d_in[2];
    const int*   tmat  = (const int*)  d_in[3];
    const float* itemw = (const float*)d_in[4];
    const float* catw  = (const float*)d_in[5];
    const float* numW  = (const float*)d_in[6];
    const float* numb  = (const float*)d_in[7];
    const float* fusW  = (const float*)d_in[8];
    const float* fusb  = (const float*)d_in[9];
    const float* elng  = (const float*)d_in[10];
    const float* elnb  = (const float*)d_in[11];
    const float* posK  = (const float*)d_in[12];
    const float* posV  = (const float*)d_in[13];
    const float* tKw   = (const float*)d_in[14];
    const float* tVw   = (const float*)d_in[15];
    const float* alng  = (const float*)d_in[16];
    const float* alnb  = (const float*)d_in[17];
    const float* QW    = (const float*)d_in[18];
    const float* Qb    = (const float*)d_in[19];
    const float* KW    = (const float*)d_in[20];
    const float* Kb    = (const float*)d_in[21];
    const float* VW    = (const float*)d_in[22];
    const float* Vb    = (const float*)d_in[23];
    const float* flng  = (const float*)d_in[24];
    const float* flnb  = (const float*)d_in[25];
    const float* w1W   = (const float*)d_in[26];
    const float* w1b   = (const float*)d_in[27];
    const float* w2W   = (const float*)d_in[28];
    const float* w2b   = (const float*)d_in[29];
    const float* llng  = (const float*)d_in[30];
    const float* llnb  = (const float*)d_in[31];
    (void)in_sizes; (void)n_in; (void)out_size; (void)ws_size;

    float* ws = (float*)d_ws;
    float* Qnp = ws + OFF_QN;
    float* Qp  = ws + OFF_Q;
    float* Kp  = ws + OFF_K;
    float* Vp  = ws + OFF_V;
    float* Op  = ws + OFF_O;
    float* outp = (float*)d_out;

    embed_qkv_kernel<<<ROWS / 2, 256, 0, stream>>>(
        ids, meta, cats, itemw, catw, numW, numb, fusW, fusb, elng, elnb,
        alng, alnb, QW, Qb, KW, Kb, VW, Vb, posK, posV, tmat, tKw, tVw,
        Qnp, Qp, Kp, Vp);
    for (int nb = 0; nb < NBn; ++nb) {
        attn_kernel<<<1024, 256, 0, stream>>>(ids, tmat, Qp, Kp, Vp, tKw, tVw, Op);
        ffn_qkv_kernel<<<ROWS / 2, 256, 0, stream>>>(
            ids, Qnp, Op, flng, flnb, w1W, w1b, w2W, w2b,
            alng, alnb, QW, Qb, KW, Kb, VW, Vb, posK, posV,
            Qp, Kp, Vp, llng, llnb, outp, nb, (nb == NBn - 1) ? 1 : 0);
    }
}